// Round 2
// baseline (507.799 us; speedup 1.0000x reference)
//
#include <hip/hip_runtime.h>
#include <math.h>
#include <stdint.h>

// N=50000, E=600000, IN_CH=64, HEADS=2, C=64, HC=128, EDGE_DIM=32
// Layouts:
//   qx  (uint/float mix): [node][128 dwords] = 64 uints bf16-packed q (both heads
//        per channel) followed by 64 floats wq interleaved [d*2+h]. One 512 B
//        record per node -> single contiguous tgt-side gather in k_alpha.
//   k/v (bf16 packed uint): [node][c] -> both heads at channel c in one uint
//   Wet (float2): [(d*64+c)] -> (We[d][h0*64+c], We[d][h1*64+c])
//   exb (float2): [node][slot] -> (ex_h0, ex_h1) in bucket order (unnormalized)
//   agg (float2): [node][c] -> (h0,h1); ALIASES qx exactly (dead after k_alpha).
// All data-derived indices are clamped: no input value can cause OOB.

__device__ __forceinline__ float wave_sum64(float v) {
#pragma unroll
    for (int m = 1; m < 64; m <<= 1) v += __shfl_xor(v, m);
    return v;
}

__device__ __forceinline__ unsigned pack_bf16(float2 v) {
    unsigned a = __builtin_bit_cast(unsigned, v.x);
    unsigned b = __builtin_bit_cast(unsigned, v.y);
    a = (a + 0x7FFFu + ((a >> 16) & 1u)) >> 16;   // RNE
    b = (b + 0x7FFFu + ((b >> 16) & 1u)) >> 16;
    return a | (b << 16);
}
__device__ __forceinline__ float2 unpack_bf16(unsigned p) {
    float x = __builtin_bit_cast(float, p << 16);
    float y = __builtin_bit_cast(float, p & 0xFFFF0000u);
    return make_float2(x, y);
}

// deg zero + work-queue counter zero + weight re-layouts, one launch.
__global__ void k_pre(const float* __restrict__ Wq, const float* __restrict__ Wk,
                      const float* __restrict__ Wv, const float* __restrict__ We,
                      const float* __restrict__ Wp, const float* __restrict__ bq,
                      const float* __restrict__ bk, const float* __restrict__ bv,
                      float* __restrict__ Wqt, float* __restrict__ Wkt,
                      float* __restrict__ Wvt, float* __restrict__ Wet,
                      float* __restrict__ Wpt, float* __restrict__ bqt,
                      float* __restrict__ bkt, float* __restrict__ bvt,
                      int* __restrict__ deg, int* __restrict__ ctr, int n) {
    int idx = blockIdx.x * 256 + threadIdx.x;
    for (int i = idx; i < n; i += gridDim.x * 256) deg[i] = 0;
    if (idx == 0) ctr[0] = 0;
    if (idx < 8192) {
        // Wq/Wk/Wv: [cin][h*64+c] -> [cin][c*2+h]
        int cin = idx >> 7, j = idx & 127, h = j >> 6, c = j & 63;
        int dst = cin * 128 + c * 2 + h;
        Wqt[dst] = Wq[idx];
        Wkt[dst] = Wk[idx];
        Wvt[dst] = Wv[idx];
        // Wp: [h*64+c][o] -> [(c*2+h)][o]
        int jin = idx >> 6, o = idx & 63, hp = jin >> 6, cp = jin & 63;
        Wpt[(cp * 2 + hp) * 64 + o] = Wp[idx];
    }
    if (idx < 4096) {
        // We: [d][h*64+c] -> [(d*64+c)*2+h]
        int d = idx >> 7, j = idx & 127, h = j >> 6, c = j & 63;
        Wet[(d * 64 + c) * 2 + h] = We[idx];
    }
    if (idx < 128) {
        int h = idx >> 6, c = idx & 63;
        bqt[c * 2 + h] = bq[idx];
        bkt[c * 2 + h] = bk[idx];
        bvt[c * 2 + h] = bv[idx];
    }
}

// Fused LN1 + QKV + wq = We^T q. One wave per EIGHT nodes (weight reuse x8).
__global__ __launch_bounds__(256) void k_qkv(
    const float* __restrict__ x,
    const float* __restrict__ Wqt, const float* __restrict__ Wkt, const float* __restrict__ Wvt,
    const float* __restrict__ bqt, const float* __restrict__ bkt, const float* __restrict__ bvt,
    const float* __restrict__ g1, const float* __restrict__ b1,
    const float* __restrict__ We,   // original [d][h*64+c]
    unsigned* __restrict__ qx, unsigned* __restrict__ kbf,
    unsigned* __restrict__ vbf, int n) {
    __shared__ __align__(16) float hT[4][64][8];     // [wave][cin][node]  8 KB
    __shared__ __align__(16) float qs[4][2][8][64];  // [wave][h][node][c] 16 KB
    int wave = threadIdx.x >> 6, lane = threadIdx.x & 63;
    int node0 = blockIdx.x * 32 + wave * 8;
    if (node0 >= n) return;

    // ---- Phase 1: LayerNorm for 8 nodes (8 lanes per node) ----
    int b = lane >> 3, t = lane & 7;
    int nodeb = node0 + b;
    float4 xa = make_float4(0.f, 0.f, 0.f, 0.f), xb = xa;
    if (nodeb < n) {
        const float4* xp = (const float4*)(x + (size_t)nodeb * 64 + t * 8);
        xa = xp[0]; xb = xp[1];
    }
    float s1 = (xa.x + xa.y) + (xa.z + xa.w) + (xb.x + xb.y) + (xb.z + xb.w);
    float s2 = xa.x*xa.x + xa.y*xa.y + xa.z*xa.z + xa.w*xa.w
             + xb.x*xb.x + xb.y*xb.y + xb.z*xb.z + xb.w*xb.w;
#pragma unroll
    for (int m = 1; m < 8; m <<= 1) {
        s1 += __shfl_xor(s1, m);
        s2 += __shfl_xor(s2, m);
    }
    float mean = s1 * 0.015625f;
    float var  = s2 * 0.015625f - mean * mean;
    float rstd = rsqrtf(var + 1e-5f);
    float4 ga = ((const float4*)(g1 + t * 8))[0];
    float4 gb = ((const float4*)(g1 + t * 8))[1];
    float4 ba = ((const float4*)(b1 + t * 8))[0];
    float4 bb = ((const float4*)(b1 + t * 8))[1];
    float hv[8];
    hv[0] = (xa.x - mean) * rstd * ga.x + ba.x;
    hv[1] = (xa.y - mean) * rstd * ga.y + ba.y;
    hv[2] = (xa.z - mean) * rstd * ga.z + ba.z;
    hv[3] = (xa.w - mean) * rstd * ga.w + ba.w;
    hv[4] = (xb.x - mean) * rstd * gb.x + bb.x;
    hv[5] = (xb.y - mean) * rstd * gb.y + bb.y;
    hv[6] = (xb.z - mean) * rstd * gb.z + bb.z;
    hv[7] = (xb.w - mean) * rstd * gb.w + bb.w;
#pragma unroll
    for (int j = 0; j < 8; ++j) hT[wave][t * 8 + j][b] = hv[j];
    // per-wave LDS, wave-lockstep: no barrier needed

    // ---- Phase 2: QKV projection, 8 nodes per weight load ----
    const float2* Wq2 = (const float2*)Wqt;
    const float2* Wk2 = (const float2*)Wkt;
    const float2* Wv2 = (const float2*)Wvt;
    float2 bqv = ((const float2*)bqt)[lane];
    float2 bkv = ((const float2*)bkt)[lane];
    float2 bvv = ((const float2*)bvt)[lane];
    float2 qa[8], ka[8], va[8];
#pragma unroll
    for (int nb = 0; nb < 8; ++nb) { qa[nb] = bqv; ka[nb] = bkv; va[nb] = bvv; }

#pragma unroll 4
    for (int cin = 0; cin < 64; ++cin) {
        float2 w_q = Wq2[cin * 64 + lane];
        float2 w_k = Wk2[cin * 64 + lane];
        float2 w_v = Wv2[cin * 64 + lane];
        const float4* hp = (const float4*)&hT[wave][cin][0];
        float4 h0 = hp[0], h1 = hp[1];   // b128 broadcast
        float hs[8] = {h0.x, h0.y, h0.z, h0.w, h1.x, h1.y, h1.z, h1.w};
#pragma unroll
        for (int nb = 0; nb < 8; ++nb) {
            qa[nb].x += hs[nb] * w_q.x; qa[nb].y += hs[nb] * w_q.y;
            ka[nb].x += hs[nb] * w_k.x; ka[nb].y += hs[nb] * w_k.y;
            va[nb].x += hs[nb] * w_v.x; va[nb].y += hs[nb] * w_v.y;
        }
    }

    // ---- Phase 3: stores + stage q in LDS for phase 4 ----
#pragma unroll
    for (int nb = 0; nb < 8; ++nb) {
        int nd = node0 + nb;
        if (nd < n) {
            qx[(size_t)nd * 128 + lane] = pack_bf16(qa[nb]);
            kbf[(size_t)nd * 64 + lane] = pack_bf16(ka[nb]);
            vbf[(size_t)nd * 64 + lane] = pack_bf16(va[nb]);
        }
        qs[wave][0][nb][lane] = qa[nb].x;
        qs[wave][1][nb][lane] = qa[nb].y;
    }

    // ---- Phase 4: wq = We^T q -> qx[node][64 + d*2 + h], 8 nodes per We load ----
    int hh = lane >> 5, d = lane & 31;
    const float4* Wr = (const float4*)(We + d * 128 + hh * 64);
    float wqa[8] = {0.f, 0.f, 0.f, 0.f, 0.f, 0.f, 0.f, 0.f};
#pragma unroll 4
    for (int c4 = 0; c4 < 16; ++c4) {
        float4 w = Wr[c4];
#pragma unroll
        for (int nb = 0; nb < 8; ++nb) {
            float4 qv = *(const float4*)&qs[wave][hh][nb][c4 * 4];  // broadcast
            wqa[nb] += w.x * qv.x + w.y * qv.y + w.z * qv.z + w.w * qv.w;
        }
    }
#pragma unroll
    for (int nb = 0; nb < 8; ++nb)
        if (node0 + nb < n)
            ((float*)qx)[(size_t)(node0 + nb) * 128 + 64 + d * 2 + hh] = wqa[nb];
}

// Edge-parallel alpha + bucket build. FOUR edges per wave (16 lanes each).
__global__ __launch_bounds__(256) void k_alpha(
    const unsigned* __restrict__ qx, const unsigned* __restrict__ kbf,
    const float* __restrict__ edge_attr,
    const int* __restrict__ ei, int* __restrict__ deg,
    int* __restrict__ bucket, float2* __restrict__ exb, int E, int n) {
    int wave = threadIdx.x >> 6, lane = threadIdx.x & 63;
    int sub = lane >> 4, l = lane & 15;
    int e = blockIdx.x * 16 + wave * 4 + sub;
    bool evalid = e < E;
    int ec = min(e, E - 1);

    int src = ei[ec];          // 16 lanes same addr -> broadcast transaction
    int tgt = ei[E + ec];
    src = min(max(src, 0), n - 1);
    tgt = min(max(tgt, 0), n - 1);

    const uint4* qx4 = (const uint4*)qx;
    uint4 qq = qx4[(size_t)tgt * 32 + l];              // q channels 4l..4l+3
    float4 w = ((const float4*)qx)[(size_t)tgt * 32 + 16 + l];  // wq dims 2l,2l+1
    uint4 kk = ((const uint4*)kbf)[(size_t)src * 16 + l];
    float2 a = ((const float2*)edge_attr)[(size_t)ec * 16 + l];

    float2 q0 = unpack_bf16(qq.x), q1 = unpack_bf16(qq.y),
           q2 = unpack_bf16(qq.z), q3 = unpack_bf16(qq.w);
    float2 k0 = unpack_bf16(kk.x), k1 = unpack_bf16(kk.y),
           k2 = unpack_bf16(kk.z), k3 = unpack_bf16(kk.w);

    float r0 = q0.x * k0.x + q1.x * k1.x + q2.x * k2.x + q3.x * k3.x
             + w.x * a.x + w.z * a.y;
    float r1 = q0.y * k0.y + q1.y * k1.y + q2.y * k2.y + q3.y * k3.y
             + w.y * a.x + w.w * a.y;
#pragma unroll
    for (int m = 1; m < 16; m <<= 1) {   // masks 1..8 stay within the 16-lane group
        r0 += __shfl_xor(r0, m);
        r1 += __shfl_xor(r1, m);
    }
    if (l == 0 && evalid) {
        int slot = atomicAdd(&deg[tgt], 1);
        if (slot < 64) {
            bucket[(size_t)tgt * 64 + slot] = ec;
            exb[(size_t)tgt * 64 + slot] =
                make_float2(__expf(r0 * 0.125f), __expf(r1 * 0.125f));
        }
    }
}

// Attention aggregation only (epilogue in k_post). One wave per node.
__global__ __launch_bounds__(256) void k_agg(
    const unsigned* __restrict__ vbf, const float2* __restrict__ exb,
    const int* __restrict__ deg, const int* __restrict__ bucket,
    const int* __restrict__ ei, const float* __restrict__ edge_attr,
    const float* __restrict__ Wet,   // float2 per (d*64+c)
    float2* __restrict__ agg, int n, int E) {
    __shared__ __align__(16) float sbuf[4][64];
    int wave = threadIdx.x >> 6, lane = threadIdx.x & 63;
    int node = blockIdx.x * 4 + wave;
    if (node >= n) return;

    int dl = lane & 31, hh = lane >> 5;

    // Coalesced preamble: lane i holds edge i's id, src, and ex pair.
    int dcount = min(deg[node], 64);
    int eid_l = 0, src_l = 0;
    float2 exl = make_float2(0.f, 0.f);
    if (lane < dcount) {
        eid_l = bucket[(size_t)node * 64 + lane];
        eid_l = min(max(eid_l, 0), E - 1);
        src_l = ei[eid_l];
        src_l = min(max(src_l, 0), n - 1);
        exl = exb[(size_t)node * 64 + lane];
    }
    float den0 = wave_sum64(exl.x);
    float den1 = wave_sum64(exl.y);

    // Padded 4-wide loop: lanes >= dcount contribute ex=0 -> zero contribution.
    float acc0 = 0.f, acc1 = 0.f, S = 0.f;
    int rounds = (dcount + 3) >> 2;
    for (int r = 0; r < rounds; ++r) {
        int i = r * 4;
        int e0 = __shfl(eid_l, i),     e1 = __shfl(eid_l, i + 1),
            e2 = __shfl(eid_l, i + 2), e3 = __shfl(eid_l, i + 3);
        int s0 = __shfl(src_l, i),     s1 = __shfl(src_l, i + 1),
            s2 = __shfl(src_l, i + 2), s3 = __shfl(src_l, i + 3);
        float x0 = __shfl(exl.x, i),     y0 = __shfl(exl.y, i);
        float x1 = __shfl(exl.x, i + 1), y1 = __shfl(exl.y, i + 1);
        float x2 = __shfl(exl.x, i + 2), y2 = __shfl(exl.y, i + 2);
        float x3 = __shfl(exl.x, i + 3), y3 = __shfl(exl.y, i + 3);
        float2 u0 = unpack_bf16(vbf[(size_t)s0 * 64 + lane]);
        float2 u1 = unpack_bf16(vbf[(size_t)s1 * 64 + lane]);
        float2 u2 = unpack_bf16(vbf[(size_t)s2 * 64 + lane]);
        float2 u3 = unpack_bf16(vbf[(size_t)s3 * 64 + lane]);
        float a0 = edge_attr[(size_t)e0 * 32 + dl];
        float a1 = edge_attr[(size_t)e1 * 32 + dl];
        float a2 = edge_attr[(size_t)e2 * 32 + dl];
        float a3 = edge_attr[(size_t)e3 * 32 + dl];
        acc0 += x0 * u0.x; acc1 += y0 * u0.y;
        acc0 += x1 * u1.x; acc1 += y1 * u1.y;
        acc0 += x2 * u2.x; acc1 += y2 * u2.y;
        acc0 += x3 * u3.x; acc1 += y3 * u3.y;
        S += (hh ? y0 : x0) * a0;
        S += (hh ? y1 : x1) * a1;
        S += (hh ? y2 : x2) * a2;
        S += (hh ? y3 : x3) * a3;
    }

    // B = We^T S : S to LDS interleaved [d*2+h], then per-lane 64 FMA.
    float* row = sbuf[wave];
    row[dl * 2 + hh] = S;
    float B0 = 0.f, B1 = 0.f;
    const float2* We2 = (const float2*)Wet;
    const float2* S2 = (const float2*)row;
#pragma unroll
    for (int d = 0; d < 32; ++d) {
        float2 w = We2[d * 64 + lane];
        float2 s = S2[d];   // LDS b64 broadcast
        B0 += w.x * s.x;
        B1 += w.y * s.y;
    }
    float r0 = 1.0f / (den0 + 1e-8f);
    float r1 = 1.0f / (den1 + 1e-8f);
    agg[(size_t)node * 64 + lane] = make_float2((acc0 + B0) * r0, (acc1 + B1) * r1);
}

// Epilogue v3: PERSISTENT blocks. 256 blocks x 1024 threads (16 waves, 1 block/CU).
// All three weight matrices staged ONCE per CU into LDS (64 KB); per-wave row
// buffers (132-stride, conflict-free) another 67.6 KB -> 133 KB LDS total.
// Waves pull 8-node chunks off a global atomic queue -> near-perfect balance.
// Inner loops read weights from LDS (group-uniform addr -> broadcast, <=2-way
// conflicts) instead of L2 (~200 cy) -> latency-bound stall removed.
// Per-channel bias/gamma/beta vectors hoisted into registers outside the loop.
__global__ __launch_bounds__(1024) void k_post(
    const float* __restrict__ agg,   // [node][128], cin = c*2+h
    const float* __restrict__ Wpt,   // [cin][64]
    const float* __restrict__ bp, const float* __restrict__ x,
    const float* __restrict__ g2, const float* __restrict__ b2,
    const float* __restrict__ W1, const float* __restrict__ b1f,
    const float* __restrict__ W2, const float* __restrict__ b2f,
    float* __restrict__ out, int* __restrict__ ctr, int n) {
    __shared__ __align__(16) float sWp[8192];         // 32 KB
    __shared__ __align__(16) float sW1[4096];         // 16 KB
    __shared__ __align__(16) float sW2[4096];         // 16 KB
    __shared__ __align__(16) float rows[16][8][132];  // 67.6 KB
    int tid = threadIdx.x;

    // Stage weights: coalesced global->LDS, once per block (= once per CU).
    {
        const float4* s = (const float4*)Wpt;
        float4* d = (float4*)sWp;
        d[tid] = s[tid];
        d[tid + 1024] = s[tid + 1024];
        ((float4*)sW1)[tid] = ((const float4*)W1)[tid];
        ((float4*)sW2)[tid] = ((const float4*)W2)[tid];
    }
    __syncthreads();

    int wave = tid >> 6, lane = tid & 63;
    int nl = lane >> 3, g = lane & 7;
    float* row = rows[wave][nl];

    // Hoist per-channel constants (depend only on g).
    float4 bp0 = ((const float4*)(bp + g * 8))[0];
    float4 bp1 = ((const float4*)(bp + g * 8))[1];
    float4 g2a = ((const float4*)(g2 + g * 8))[0];
    float4 g2b = ((const float4*)(g2 + g * 8))[1];
    float4 bb2a = ((const float4*)(b2 + g * 8))[0];
    float4 bb2b = ((const float4*)(b2 + g * 8))[1];
    float4 f1a = ((const float4*)(b1f + g * 8))[0];
    float4 f1b = ((const float4*)(b1f + g * 8))[1];
    float4 f2a = ((const float4*)(b2f + g * 8))[0];
    float4 f2b = ((const float4*)(b2f + g * 8))[1];

    int nchunks = (n + 7) >> 3;
    for (;;) {
        int cv = 0;
        if (lane == 0) cv = atomicAdd(ctr, 1);
        int chunk = __shfl(cv, 0);
        if (chunk >= nchunks) break;
        int node = chunk * 8 + nl;
        bool valid = node < n;
        int nd = min(node, n - 1);

        // Stage agg row: 16 floats per thread, coalesced global -> LDS.
        {
            const float4* ap = (const float4*)(agg + (size_t)nd * 128 + g * 16);
            float4 a0 = ap[0], a1 = ap[1], a2 = ap[2], a3 = ap[3];
            float4* rp = (float4*)(row + g * 16);
            rp[0] = a0; rp[1] = a1; rp[2] = a2; rp[3] = a3;
        }

        // acc = bp + x (residual 1)
        float acc[8];
        {
            const float4* xp = (const float4*)(x + (size_t)nd * 64 + g * 8);
            float4 x0 = xp[0], x1 = xp[1];
            acc[0] = bp0.x + x0.x;  acc[1] = bp0.y + x0.y;
            acc[2] = bp0.z + x0.z;  acc[3] = bp0.w + x0.w;
            acc[4] = bp1.x + x1.x;  acc[5] = bp1.y + x1.y;
            acc[6] = bp1.z + x1.z;  acc[7] = bp1.w + x1.w;
        }

        // acc += agg @ Wp  (128 cins; agg via LDS b128 broadcast, weights in LDS)
#pragma unroll 4
        for (int c4 = 0; c4 < 32; ++c4) {
            float4 a = *(const float4*)(row + c4 * 4);
            float as[4] = {a.x, a.y, a.z, a.w};
#pragma unroll
            for (int j = 0; j < 4; ++j) {
                const float4* wp = (const float4*)(sWp + (c4 * 4 + j) * 64 + g * 8);
                float4 w0 = wp[0], w1 = wp[1];
                acc[0] += as[j] * w0.x; acc[1] += as[j] * w0.y;
                acc[2] += as[j] * w0.z; acc[3] += as[j] * w0.w;
                acc[4] += as[j] * w1.x; acc[5] += as[j] * w1.y;
                acc[6] += as[j] * w1.z; acc[7] += as[j] * w1.w;
            }
        }

        // LN2: 8 local + 3-step group reduction
        float s1 = 0.f, s2 = 0.f;
#pragma unroll
        for (int c = 0; c < 8; ++c) { s1 += acc[c]; s2 += acc[c] * acc[c]; }
#pragma unroll
        for (int m = 1; m < 8; m <<= 1) {
            s1 += __shfl_xor(s1, m);
            s2 += __shfl_xor(s2, m);
        }
        float mean = s1 * 0.015625f;
        float var  = s2 * 0.015625f - mean * mean;
        float rstd = rsqrtf(var + 1e-5f);
        {
            float h2[8];
            h2[0] = (acc[0] - mean) * rstd * g2a.x + bb2a.x;
            h2[1] = (acc[1] - mean) * rstd * g2a.y + bb2a.y;
            h2[2] = (acc[2] - mean) * rstd * g2a.z + bb2a.z;
            h2[3] = (acc[3] - mean) * rstd * g2a.w + bb2a.w;
            h2[4] = (acc[4] - mean) * rstd * g2b.x + bb2b.x;
            h2[5] = (acc[5] - mean) * rstd * g2b.y + bb2b.y;
            h2[6] = (acc[6] - mean) * rstd * g2b.z + bb2b.z;
            h2[7] = (acc[7] - mean) * rstd * g2b.w + bb2b.w;
            float4* rp = (float4*)(row + g * 8);    // h2 at row[0..63]
            rp[0] = make_float4(h2[0], h2[1], h2[2], h2[3]);
            rp[1] = make_float4(h2[4], h2[5], h2[6], h2[7]);
        }

        // f = h2 @ W1 + b1; gelu -> row[64..127]
        float f[8];
        f[0] = f1a.x; f[1] = f1a.y; f[2] = f1a.z; f[3] = f1a.w;
        f[4] = f1b.x; f[5] = f1b.y; f[6] = f1b.z; f[7] = f1b.w;
#pragma unroll 4
        for (int c4 = 0; c4 < 16; ++c4) {
            float4 a = *(const float4*)(row + c4 * 4);
            float as[4] = {a.x, a.y, a.z, a.w};
#pragma unroll
            for (int j = 0; j < 4; ++j) {
                const float4* wp = (const float4*)(sW1 + (c4 * 4 + j) * 64 + g * 8);
                float4 w0 = wp[0], w1 = wp[1];
                f[0] += as[j] * w0.x; f[1] += as[j] * w0.y;
                f[2] += as[j] * w0.z; f[3] += as[j] * w0.w;
                f[4] += as[j] * w1.x; f[5] += as[j] * w1.y;
                f[6] += as[j] * w1.z; f[7] += as[j] * w1.w;
            }
        }
#pragma unroll
        for (int c = 0; c < 8; ++c)
            f[c] = 0.5f * f[c] * (1.0f + erff(f[c] * 0.70710678118654752f));
        {
            float4* rp = (float4*)(row + 64 + g * 8);
            rp[0] = make_float4(f[0], f[1], f[2], f[3]);
            rp[1] = make_float4(f[4], f[5], f[6], f[7]);
        }

        // y = gelu @ W2 + b2f + acc (residual 2)
        float y[8];
        y[0] = f2a.x + acc[0]; y[1] = f2a.y + acc[1];
        y[2] = f2a.z + acc[2]; y[3] = f2a.w + acc[3];
        y[4] = f2b.x + acc[4]; y[5] = f2b.y + acc[5];
        y[6] = f2b.z + acc[6]; y[7] = f2b.w + acc[7];
#pragma unroll 4
        for (int c4 = 0; c4 < 16; ++c4) {
            float4 a = *(const float4*)(row + 64 + c4 * 4);
            float as[4] = {a.x, a.y, a.z, a.w};
#pragma unroll
            for (int j = 0; j < 4; ++j) {
                const float4* wp = (const float4*)(sW2 + (c4 * 4 + j) * 64 + g * 8);
                float4 w0 = wp[0], w1 = wp[1];
                y[0] += as[j] * w0.x; y[1] += as[j] * w0.y;
                y[2] += as[j] * w0.z; y[3] += as[j] * w0.w;
                y[4] += as[j] * w1.x; y[5] += as[j] * w1.y;
                y[6] += as[j] * w1.z; y[7] += as[j] * w1.w;
            }
        }

        if (valid) {
            float4* op = (float4*)(out + (size_t)node * 64 + g * 8);
            op[0] = make_float4(y[0], y[1], y[2], y[3]);
            op[1] = make_float4(y[4], y[5], y[6], y[7]);
        }
    }
}

extern "C" void kernel_launch(void* const* d_in, const int* in_sizes, int n_in,
                              void* d_out, int out_size, void* d_ws, size_t ws_size,
                              hipStream_t stream) {
    const float* x  = (const float*)d_in[0];
    const int*   ei = (const int*)d_in[1];
    const float* ea = (const float*)d_in[2];
    const float* Wq = (const float*)d_in[3];
    const float* bq = (const float*)d_in[4];
    const float* Wk = (const float*)d_in[5];
    const float* bk = (const float*)d_in[6];
    const float* Wv = (const float*)d_in[7];
    const float* bv = (const float*)d_in[8];
    const float* We = (const float*)d_in[9];
    const float* Wp = (const float*)d_in[10];
    const float* bp = (const float*)d_in[11];
    const float* g1 = (const float*)d_in[12];
    const float* b1 = (const float*)d_in[13];
    const float* g2 = (const float*)d_in[14];
    const float* b2 = (const float*)d_in[15];
    const float* W1 = (const float*)d_in[16];
    const float* b1f = (const float*)d_in[17];
    const float* W2 = (const float*)d_in[18];
    const float* b2f = (const float*)d_in[19];

    const int n = in_sizes[0] / 64;   // 50000
    const int E = in_sizes[2] / 32;   // 600000

    // Workspace carve (~90.0 MB, proven layout).
    // agg (n*128 floats) ALIASES qx exactly (qx dead after k_alpha).
    char* p = (char*)d_ws;
    unsigned* qx = (unsigned*)p; p += (size_t)n * 128 * 4;   // q bf16 + wq fused
    float* aggb = (float*)qx;
    unsigned* kbf = (unsigned*)p; p += (size_t)n * 64 * 4;
    unsigned* vbf = (unsigned*)p; p += (size_t)n * 64 * 4;
    int* deg   = (int*)p;   p += (size_t)n * 4;
    p = (char*)(((uintptr_t)p + 15) & ~(uintptr_t)15);
    int* bucket = (int*)p;  p += (size_t)n * 64 * 4;
    float2* exb = (float2*)p; p += (size_t)n * 64 * 8;
    float* Wqt = (float*)p; p += 8192 * 4;
    float* Wkt = (float*)p; p += 8192 * 4;
    float* Wvt = (float*)p; p += 8192 * 4;
    float* Wet = (float*)p; p += 4096 * 4;
    float* Wpt = (float*)p; p += 8192 * 4;
    float* bqt = (float*)p; p += 128 * 4;
    float* bkt = (float*)p; p += 128 * 4;
    float* bvt = (float*)p; p += 128 * 4;
    int* ctr = (int*)p; p += 4;

    k_pre<<<196, 256, 0, stream>>>(Wq, Wk, Wv, We, Wp, bq, bk, bv,
                                   Wqt, Wkt, Wvt, Wet, Wpt, bqt, bkt, bvt,
                                   deg, ctr, n);
    k_qkv<<<(n + 31) / 32, 256, 0, stream>>>(x, Wqt, Wkt, Wvt, bqt, bkt, bvt,
                                             g1, b1, We, qx, kbf, vbf, n);
    k_alpha<<<(E + 15) / 16, 256, 0, stream>>>(qx, kbf, ea, ei,
                                               deg, bucket, exb, E, n);
    k_agg<<<(n + 3) / 4, 256, 0, stream>>>(vbf, exb, deg, bucket, ei, ea,
                                           Wet, (float2*)aggb, n, E);
    k_post<<<256, 1024, 0, stream>>>(aggb, Wpt, bp, x, g2, b2,
                                     W1, b1f, W2, b2f,
                                     (float*)d_out, ctr, n);
}

// Round 3
// 397.169 us; speedup vs baseline: 1.2785x; 1.2785x over previous
//
#include <hip/hip_runtime.h>
#include <math.h>
#include <stdint.h>

// N=50000, E=600000, IN_CH=64, HEADS=2, C=64, HC=128, EDGE_DIM=32
// Layouts:
//   qx  (uint/float mix): [node][128 dwords] = 64 uints bf16-packed q (both heads
//        per channel) followed by 64 floats wq interleaved [d*2+h].
//   k/v (bf16 packed uint): [node][c] -> both heads at channel c in one uint
//   Wet (float2): [(d*64+c)] -> (We[d][h0*64+c], We[d][h1*64+c])
//   exb (float2): [node][slot] -> (ex_h0, ex_h1) in bucket order (unnormalized)
//   aggbf (bf16 ushort): [node][cin=c*2+h], 128 bf16/row; ALIASES qx.
//   wsW (bf16 ushort): WpT[o][k]@stride152 | W1T[o][k]@88 | W2T[o][k]@88
//        (k-contiguous [N][K] rows, 16B-aligned strides, pad cols never read)
// All data-derived indices are clamped: no input value can cause OOB.

typedef float f32x4 __attribute__((ext_vector_type(4)));
typedef __bf16 bf16x8 __attribute__((ext_vector_type(8)));
typedef unsigned int u32x4 __attribute__((ext_vector_type(4)));

#define WP_S 152
#define W1_OFF 9728
#define W2_OFF 15360
#define W_TOT 20992
#define H_S 72

__device__ __forceinline__ float wave_sum64(float v) {
#pragma unroll
    for (int m = 1; m < 64; m <<= 1) v += __shfl_xor(v, m);
    return v;
}

__device__ __forceinline__ unsigned pack_bf16(float2 v) {
    unsigned a = __builtin_bit_cast(unsigned, v.x);
    unsigned b = __builtin_bit_cast(unsigned, v.y);
    a = (a + 0x7FFFu + ((a >> 16) & 1u)) >> 16;   // RNE
    b = (b + 0x7FFFu + ((b >> 16) & 1u)) >> 16;
    return a | (b << 16);
}
__device__ __forceinline__ float2 unpack_bf16(unsigned p) {
    float x = __builtin_bit_cast(float, p << 16);
    float y = __builtin_bit_cast(float, p & 0xFFFF0000u);
    return make_float2(x, y);
}
__device__ __forceinline__ unsigned short bf16r(float x) {
    unsigned u = __builtin_bit_cast(unsigned, x);
    return (unsigned short)((u + 0x7FFFu + ((u >> 16) & 1u)) >> 16);
}

__device__ __forceinline__ f32x4 mfma16(bf16x8 a, bf16x8 b, f32x4 c) {
    return __builtin_amdgcn_mfma_f32_16x16x32_bf16(a, b, c, 0, 0, 0);
}
__device__ __forceinline__ bf16x8 frag_ld(const unsigned short* p) {
    return __builtin_bit_cast(bf16x8, *(const u32x4*)p);
}

// deg zero + weight re-layouts (incl. bf16-transposed FFN weights), one launch.
__global__ void k_pre(const float* __restrict__ Wq, const float* __restrict__ Wk,
                      const float* __restrict__ Wv, const float* __restrict__ We,
                      const float* __restrict__ Wp, const float* __restrict__ W1,
                      const float* __restrict__ W2, const float* __restrict__ bq,
                      const float* __restrict__ bk, const float* __restrict__ bv,
                      float* __restrict__ Wqt, float* __restrict__ Wkt,
                      float* __restrict__ Wvt, float* __restrict__ Wet,
                      unsigned short* __restrict__ wsW, float* __restrict__ bqt,
                      float* __restrict__ bkt, float* __restrict__ bvt,
                      int* __restrict__ deg, int n) {
    int idx = blockIdx.x * 256 + threadIdx.x;
    for (int i = idx; i < n; i += gridDim.x * 256) deg[i] = 0;
    if (idx < 8192) {
        // Wq/Wk/Wv: [cin][h*64+c] -> [cin][c*2+h]
        int cin = idx >> 7, j = idx & 127, h = j >> 6, c = j & 63;
        int dst = cin * 128 + c * 2 + h;
        Wqt[dst] = Wq[idx];
        Wkt[dst] = Wk[idx];
        Wvt[dst] = Wv[idx];
        // WpT bf16 [o][k], k=cin=c*2+h -> orig row (k&1)*64 + (k>>1)
        int o = idx >> 7, k = idx & 127;
        wsW[o * WP_S + k] = bf16r(Wp[((k & 1) * 64 + (k >> 1)) * 64 + o]);
    }
    if (idx < 4096) {
        // We: [d][h*64+c] -> [(d*64+c)*2+h]
        int d = idx >> 7, j = idx & 127, h = j >> 6, c = j & 63;
        Wet[(d * 64 + c) * 2 + h] = We[idx];
        // W1T/W2T bf16 [o][k]
        int o = idx >> 6, k = idx & 63;
        wsW[W1_OFF + o * 88 + k] = bf16r(W1[k * 64 + o]);
        wsW[W2_OFF + o * 88 + k] = bf16r(W2[k * 64 + o]);
    }
    if (idx < 128) {
        int h = idx >> 6, c = idx & 63;
        bqt[c * 2 + h] = bq[idx];
        bkt[c * 2 + h] = bk[idx];
        bvt[c * 2 + h] = bv[idx];
    }
}

// Fused LN1 + QKV + wq = We^T q. One wave per EIGHT nodes (weight reuse x8).
__global__ __launch_bounds__(256) void k_qkv(
    const float* __restrict__ x,
    const float* __restrict__ Wqt, const float* __restrict__ Wkt, const float* __restrict__ Wvt,
    const float* __restrict__ bqt, const float* __restrict__ bkt, const float* __restrict__ bvt,
    const float* __restrict__ g1, const float* __restrict__ b1,
    const float* __restrict__ We,   // original [d][h*64+c]
    unsigned* __restrict__ qx, unsigned* __restrict__ kbf,
    unsigned* __restrict__ vbf, int n) {
    __shared__ __align__(16) float hT[4][64][8];     // [wave][cin][node]  8 KB
    __shared__ __align__(16) float qs[4][2][8][64];  // [wave][h][node][c] 16 KB
    int wave = threadIdx.x >> 6, lane = threadIdx.x & 63;
    int node0 = blockIdx.x * 32 + wave * 8;
    if (node0 >= n) return;

    // ---- Phase 1: LayerNorm for 8 nodes (8 lanes per node) ----
    int b = lane >> 3, t = lane & 7;
    int nodeb = node0 + b;
    float4 xa = make_float4(0.f, 0.f, 0.f, 0.f), xb = xa;
    if (nodeb < n) {
        const float4* xp = (const float4*)(x + (size_t)nodeb * 64 + t * 8);
        xa = xp[0]; xb = xp[1];
    }
    float s1 = (xa.x + xa.y) + (xa.z + xa.w) + (xb.x + xb.y) + (xb.z + xb.w);
    float s2 = xa.x*xa.x + xa.y*xa.y + xa.z*xa.z + xa.w*xa.w
             + xb.x*xb.x + xb.y*xb.y + xb.z*xb.z + xb.w*xb.w;
#pragma unroll
    for (int m = 1; m < 8; m <<= 1) {
        s1 += __shfl_xor(s1, m);
        s2 += __shfl_xor(s2, m);
    }
    float mean = s1 * 0.015625f;
    float var  = s2 * 0.015625f - mean * mean;
    float rstd = rsqrtf(var + 1e-5f);
    float4 ga = ((const float4*)(g1 + t * 8))[0];
    float4 gb = ((const float4*)(g1 + t * 8))[1];
    float4 ba = ((const float4*)(b1 + t * 8))[0];
    float4 bb = ((const float4*)(b1 + t * 8))[1];
    float hv[8];
    hv[0] = (xa.x - mean) * rstd * ga.x + ba.x;
    hv[1] = (xa.y - mean) * rstd * ga.y + ba.y;
    hv[2] = (xa.z - mean) * rstd * ga.z + ba.z;
    hv[3] = (xa.w - mean) * rstd * ga.w + ba.w;
    hv[4] = (xb.x - mean) * rstd * gb.x + bb.x;
    hv[5] = (xb.y - mean) * rstd * gb.y + bb.y;
    hv[6] = (xb.z - mean) * rstd * gb.z + bb.z;
    hv[7] = (xb.w - mean) * rstd * gb.w + bb.w;
#pragma unroll
    for (int j = 0; j < 8; ++j) hT[wave][t * 8 + j][b] = hv[j];
    // per-wave LDS, wave-lockstep: no barrier needed

    // ---- Phase 2: QKV projection, 8 nodes per weight load ----
    const float2* Wq2 = (const float2*)Wqt;
    const float2* Wk2 = (const float2*)Wkt;
    const float2* Wv2 = (const float2*)Wvt;
    float2 bqv = ((const float2*)bqt)[lane];
    float2 bkv = ((const float2*)bkt)[lane];
    float2 bvv = ((const float2*)bvt)[lane];
    float2 qa[8], ka[8], va[8];
#pragma unroll
    for (int nb = 0; nb < 8; ++nb) { qa[nb] = bqv; ka[nb] = bkv; va[nb] = bvv; }

#pragma unroll 4
    for (int cin = 0; cin < 64; ++cin) {
        float2 w_q = Wq2[cin * 64 + lane];
        float2 w_k = Wk2[cin * 64 + lane];
        float2 w_v = Wv2[cin * 64 + lane];
        const float4* hp = (const float4*)&hT[wave][cin][0];
        float4 h0 = hp[0], h1 = hp[1];   // b128 broadcast
        float hs[8] = {h0.x, h0.y, h0.z, h0.w, h1.x, h1.y, h1.z, h1.w};
#pragma unroll
        for (int nb = 0; nb < 8; ++nb) {
            qa[nb].x += hs[nb] * w_q.x; qa[nb].y += hs[nb] * w_q.y;
            ka[nb].x += hs[nb] * w_k.x; ka[nb].y += hs[nb] * w_k.y;
            va[nb].x += hs[nb] * w_v.x; va[nb].y += hs[nb] * w_v.y;
        }
    }

    // ---- Phase 3: stores + stage q in LDS for phase 4 ----
#pragma unroll
    for (int nb = 0; nb < 8; ++nb) {
        int nd = node0 + nb;
        if (nd < n) {
            qx[(size_t)nd * 128 + lane] = pack_bf16(qa[nb]);
            kbf[(size_t)nd * 64 + lane] = pack_bf16(ka[nb]);
            vbf[(size_t)nd * 64 + lane] = pack_bf16(va[nb]);
        }
        qs[wave][0][nb][lane] = qa[nb].x;
        qs[wave][1][nb][lane] = qa[nb].y;
    }

    // ---- Phase 4: wq = We^T q -> qx[node][64 + d*2 + h], 8 nodes per We load ----
    int hh = lane >> 5, d = lane & 31;
    const float4* Wr = (const float4*)(We + d * 128 + hh * 64);
    float wqa[8] = {0.f, 0.f, 0.f, 0.f, 0.f, 0.f, 0.f, 0.f};
#pragma unroll 4
    for (int c4 = 0; c4 < 16; ++c4) {
        float4 w = Wr[c4];
#pragma unroll
        for (int nb = 0; nb < 8; ++nb) {
            float4 qv = *(const float4*)&qs[wave][hh][nb][c4 * 4];  // broadcast
            wqa[nb] += w.x * qv.x + w.y * qv.y + w.z * qv.z + w.w * qv.w;
        }
    }
#pragma unroll
    for (int nb = 0; nb < 8; ++nb)
        if (node0 + nb < n)
            ((float*)qx)[(size_t)(node0 + nb) * 128 + 64 + d * 2 + hh] = wqa[nb];
}

// Edge-parallel alpha + bucket build. FOUR edges per wave (16 lanes each).
__global__ __launch_bounds__(256) void k_alpha(
    const unsigned* __restrict__ qx, const unsigned* __restrict__ kbf,
    const float* __restrict__ edge_attr,
    const int* __restrict__ ei, int* __restrict__ deg,
    int* __restrict__ bucket, float2* __restrict__ exb, int E, int n) {
    int wave = threadIdx.x >> 6, lane = threadIdx.x & 63;
    int sub = lane >> 4, l = lane & 15;
    int e = blockIdx.x * 16 + wave * 4 + sub;
    bool evalid = e < E;
    int ec = min(e, E - 1);

    int src = ei[ec];          // 16 lanes same addr -> broadcast transaction
    int tgt = ei[E + ec];
    src = min(max(src, 0), n - 1);
    tgt = min(max(tgt, 0), n - 1);

    const uint4* qx4 = (const uint4*)qx;
    uint4 qq = qx4[(size_t)tgt * 32 + l];              // q channels 4l..4l+3
    float4 w = ((const float4*)qx)[(size_t)tgt * 32 + 16 + l];  // wq dims 2l,2l+1
    uint4 kk = ((const uint4*)kbf)[(size_t)src * 16 + l];
    float2 a = ((const float2*)edge_attr)[(size_t)ec * 16 + l];

    float2 q0 = unpack_bf16(qq.x), q1 = unpack_bf16(qq.y),
           q2 = unpack_bf16(qq.z), q3 = unpack_bf16(qq.w);
    float2 k0 = unpack_bf16(kk.x), k1 = unpack_bf16(kk.y),
           k2 = unpack_bf16(kk.z), k3 = unpack_bf16(kk.w);

    float r0 = q0.x * k0.x + q1.x * k1.x + q2.x * k2.x + q3.x * k3.x
             + w.x * a.x + w.z * a.y;
    float r1 = q0.y * k0.y + q1.y * k1.y + q2.y * k2.y + q3.y * k3.y
             + w.y * a.x + w.w * a.y;
#pragma unroll
    for (int m = 1; m < 16; m <<= 1) {   // masks 1..8 stay within the 16-lane group
        r0 += __shfl_xor(r0, m);
        r1 += __shfl_xor(r1, m);
    }
    if (l == 0 && evalid) {
        int slot = atomicAdd(&deg[tgt], 1);
        if (slot < 64) {
            bucket[(size_t)tgt * 64 + slot] = ec;
            exb[(size_t)tgt * 64 + slot] =
                make_float2(__expf(r0 * 0.125f), __expf(r1 * 0.125f));
        }
    }
}

// Attention aggregation only (epilogue in k_post). One wave per node.
// Output agg now PACKED BF16 (uint = (h0,h1) per channel) for MFMA k_post.
__global__ __launch_bounds__(256) void k_agg(
    const unsigned* __restrict__ vbf, const float2* __restrict__ exb,
    const int* __restrict__ deg, const int* __restrict__ bucket,
    const int* __restrict__ ei, const float* __restrict__ edge_attr,
    const float* __restrict__ Wet,   // float2 per (d*64+c)
    unsigned* __restrict__ agg, int n, int E) {
    __shared__ __align__(16) float sbuf[4][64];
    int wave = threadIdx.x >> 6, lane = threadIdx.x & 63;
    int node = blockIdx.x * 4 + wave;
    if (node >= n) return;

    int dl = lane & 31, hh = lane >> 5;

    // Coalesced preamble: lane i holds edge i's id, src, and ex pair.
    int dcount = min(deg[node], 64);
    int eid_l = 0, src_l = 0;
    float2 exl = make_float2(0.f, 0.f);
    if (lane < dcount) {
        eid_l = bucket[(size_t)node * 64 + lane];
        eid_l = min(max(eid_l, 0), E - 1);
        src_l = ei[eid_l];
        src_l = min(max(src_l, 0), n - 1);
        exl = exb[(size_t)node * 64 + lane];
    }
    float den0 = wave_sum64(exl.x);
    float den1 = wave_sum64(exl.y);

    // Padded 4-wide loop: lanes >= dcount contribute ex=0 -> zero contribution.
    float acc0 = 0.f, acc1 = 0.f, S = 0.f;
    int rounds = (dcount + 3) >> 2;
    for (int r = 0; r < rounds; ++r) {
        int i = r * 4;
        int e0 = __shfl(eid_l, i),     e1 = __shfl(eid_l, i + 1),
            e2 = __shfl(eid_l, i + 2), e3 = __shfl(eid_l, i + 3);
        int s0 = __shfl(src_l, i),     s1 = __shfl(src_l, i + 1),
            s2 = __shfl(src_l, i + 2), s3 = __shfl(src_l, i + 3);
        float x0 = __shfl(exl.x, i),     y0 = __shfl(exl.y, i);
        float x1 = __shfl(exl.x, i + 1), y1 = __shfl(exl.y, i + 1);
        float x2 = __shfl(exl.x, i + 2), y2 = __shfl(exl.y, i + 2);
        float x3 = __shfl(exl.x, i + 3), y3 = __shfl(exl.y, i + 3);
        float2 u0 = unpack_bf16(vbf[(size_t)s0 * 64 + lane]);
        float2 u1 = unpack_bf16(vbf[(size_t)s1 * 64 + lane]);
        float2 u2 = unpack_bf16(vbf[(size_t)s2 * 64 + lane]);
        float2 u3 = unpack_bf16(vbf[(size_t)s3 * 64 + lane]);
        float a0 = edge_attr[(size_t)e0 * 32 + dl];
        float a1 = edge_attr[(size_t)e1 * 32 + dl];
        float a2 = edge_attr[(size_t)e2 * 32 + dl];
        float a3 = edge_attr[(size_t)e3 * 32 + dl];
        acc0 += x0 * u0.x; acc1 += y0 * u0.y;
        acc0 += x1 * u1.x; acc1 += y1 * u1.y;
        acc0 += x2 * u2.x; acc1 += y2 * u2.y;
        acc0 += x3 * u3.x; acc1 += y3 * u3.y;
        S += (hh ? y0 : x0) * a0;
        S += (hh ? y1 : x1) * a1;
        S += (hh ? y2 : x2) * a2;
        S += (hh ? y3 : x3) * a3;
    }

    // B = We^T S : S to LDS interleaved [d*2+h], then per-lane 64 FMA.
    float* row = sbuf[wave];
    row[dl * 2 + hh] = S;
    float B0 = 0.f, B1 = 0.f;
    const float2* We2 = (const float2*)Wet;
    const float2* S2 = (const float2*)row;
#pragma unroll
    for (int d = 0; d < 32; ++d) {
        float2 w = We2[d * 64 + lane];
        float2 s = S2[d];   // LDS b64 broadcast
        B0 += w.x * s.x;
        B1 += w.y * s.y;
    }
    float r0 = 1.0f / (den0 + 1e-8f);
    float r1 = 1.0f / (den1 + 1e-8f);
    agg[(size_t)node * 64 + lane] =
        pack_bf16(make_float2((acc0 + B0) * r0, (acc1 + B1) * r1));
}

// Epilogue v4: MFMA. One wave per 16 nodes; 3 GEMMs via mfma_f32_16x16x32_bf16.
// C/D frag: col=lane&15, row=(lane>>4)*4+reg [m89-verified]. A=[M][K] rows,
// B=[N][K] rows (k-contiguous, b128 frags). Weights staged bf16 in LDS (42 KB),
// per-wave h2/h3 transpose buffers (4.6 KB) -> 60.4 KB/block, 2 blocks/CU.
// LN2 via 16-lane shfl_xor on the C-layout. fp32 accum throughout; bf16 only
// on GEMM inputs. ~32 MFMA + ~100 LDS + ~350 VALU per 16 nodes (was ~9200).
__global__ __launch_bounds__(256) void k_post(
    const unsigned short* __restrict__ aggbf,  // [node][128] bf16, cin=c*2+h
    const unsigned short* __restrict__ wsW,    // packed WpT|W1T|W2T bf16
    const float* __restrict__ bp, const float* __restrict__ x,
    const float* __restrict__ g2, const float* __restrict__ b2,
    const float* __restrict__ b1f, const float* __restrict__ b2f,
    float* __restrict__ out, int n) {
    __shared__ __align__(16) unsigned short sW[W_TOT];        // 41984 B
    __shared__ __align__(16) unsigned short hb[4][2][16 * H_S];  // 18432 B
    int tid = threadIdx.x;
    for (int i = tid; i < W_TOT / 8; i += 256)
        ((u32x4*)sW)[i] = ((const u32x4*)wsW)[i];
    __syncthreads();

    int wave = tid >> 6, lane = tid & 63;
    int cl = lane & 15, kg = lane >> 4;   // col-lane, k-group
    unsigned short* h2 = hb[wave][0];
    unsigned short* h3 = hb[wave][1];

    // hoisted per-column constants: c = t*16 + cl
    float bp_c[4], g2_c[4], b2_c[4], b1_c[4], bf2_c[4];
#pragma unroll
    for (int t = 0; t < 4; ++t) {
        int c = t * 16 + cl;
        bp_c[t] = bp[c];
        g2_c[t] = g2[c];
        b2_c[t] = b2[c];
        b1_c[t] = b1f[c];
        bf2_c[t] = b2f[c];
    }

    int wid = blockIdx.x * 4 + wave;
    int nbatch = (n + 15) >> 4;
    int nwaves = gridDim.x * 4;
    for (int bt = wid; bt < nbatch; bt += nwaves) {
        int node0 = bt * 16;

        // ---- GEMM1: acc1 = agg(16x128,bf16) @ Wp + bp + x ----
        f32x4 acc1[4];
#pragma unroll
        for (int t = 0; t < 4; ++t) acc1[t] = (f32x4){0.f, 0.f, 0.f, 0.f};
        int arow = min(node0 + cl, n - 1);
#pragma unroll
        for (int s = 0; s < 4; ++s) {
            bf16x8 af = frag_ld(aggbf + (size_t)arow * 128 + s * 32 + kg * 8);
#pragma unroll
            for (int t = 0; t < 4; ++t) {
                bf16x8 bf = frag_ld(sW + (t * 16 + cl) * WP_S + s * 32 + kg * 8);
                acc1[t] = mfma16(af, bf, acc1[t]);
            }
        }
#pragma unroll
        for (int t = 0; t < 4; ++t) {
#pragma unroll
            for (int j = 0; j < 4; ++j) {
                int nd = min(node0 + kg * 4 + j, n - 1);
                acc1[t][j] += bp_c[t] + x[(size_t)nd * 64 + t * 16 + cl];
            }
        }

        // ---- LN2 over 64 channels of rows r = kg*4+j ----
        float mean[4], rstd[4];
#pragma unroll
        for (int j = 0; j < 4; ++j) {
            float s1 = acc1[0][j] + acc1[1][j] + acc1[2][j] + acc1[3][j];
            float s2 = acc1[0][j] * acc1[0][j] + acc1[1][j] * acc1[1][j]
                     + acc1[2][j] * acc1[2][j] + acc1[3][j] * acc1[3][j];
#pragma unroll
            for (int m = 1; m < 16; m <<= 1) {
                s1 += __shfl_xor(s1, m);
                s2 += __shfl_xor(s2, m);
            }
            mean[j] = s1 * 0.015625f;
            float var = s2 * 0.015625f - mean[j] * mean[j];
            rstd[j] = rsqrtf(var + 1e-5f);
        }
#pragma unroll
        for (int t = 0; t < 4; ++t)
#pragma unroll
            for (int j = 0; j < 4; ++j) {
                float v = (acc1[t][j] - mean[j]) * rstd[j] * g2_c[t] + b2_c[t];
                h2[(kg * 4 + j) * H_S + t * 16 + cl] = bf16r(v);
            }
        asm volatile("s_waitcnt lgkmcnt(0)" ::: "memory");

        // ---- GEMM2: f = h2(16x64) @ W1 + b1; gelu -> h3 ----
        f32x4 acc2[4];
#pragma unroll
        for (int t = 0; t < 4; ++t)
            acc2[t] = (f32x4){b1_c[t], b1_c[t], b1_c[t], b1_c[t]};
#pragma unroll
        for (int s = 0; s < 2; ++s) {
            bf16x8 af = frag_ld(h2 + cl * H_S + s * 32 + kg * 8);
#pragma unroll
            for (int t = 0; t < 4; ++t) {
                bf16x8 bf = frag_ld(sW + W1_OFF + (t * 16 + cl) * 88 + s * 32 + kg * 8);
                acc2[t] = mfma16(af, bf, acc2[t]);
            }
        }
#pragma unroll
        for (int t = 0; t < 4; ++t)
#pragma unroll
            for (int j = 0; j < 4; ++j) {
                float v = acc2[t][j];
                v = 0.5f * v * (1.0f + erff(v * 0.70710678118654752f));
                h3[(kg * 4 + j) * H_S + t * 16 + cl] = bf16r(v);
            }
        asm volatile("s_waitcnt lgkmcnt(0)" ::: "memory");

        // ---- GEMM3: y = gelu @ W2 + b2f + acc1 (residual 2) ----
        f32x4 acc3[4];
#pragma unroll
        for (int t = 0; t < 4; ++t) {
            acc3[t] = acc1[t];
#pragma unroll
            for (int j = 0; j < 4; ++j) acc3[t][j] += bf2_c[t];
        }
#pragma unroll
        for (int s = 0; s < 2; ++s) {
            bf16x8 af = frag_ld(h3 + cl * H_S + s * 32 + kg * 8);
#pragma unroll
            for (int t = 0; t < 4; ++t) {
                bf16x8 bf = frag_ld(sW + W2_OFF + (t * 16 + cl) * 88 + s * 32 + kg * 8);
                acc3[t] = mfma16(af, bf, acc3[t]);
            }
        }
#pragma unroll
        for (int t = 0; t < 4; ++t)
#pragma unroll
            for (int j = 0; j < 4; ++j) {
                int r = node0 + kg * 4 + j;
                if (r < n) out[(size_t)r * 64 + t * 16 + cl] = acc3[t][j];
            }
    }
}

extern "C" void kernel_launch(void* const* d_in, const int* in_sizes, int n_in,
                              void* d_out, int out_size, void* d_ws, size_t ws_size,
                              hipStream_t stream) {
    const float* x  = (const float*)d_in[0];
    const int*   ei = (const int*)d_in[1];
    const float* ea = (const float*)d_in[2];
    const float* Wq = (const float*)d_in[3];
    const float* bq = (const float*)d_in[4];
    const float* Wk = (const float*)d_in[5];
    const float* bk = (const float*)d_in[6];
    const float* Wv = (const float*)d_in[7];
    const float* bv = (const float*)d_in[8];
    const float* We = (const float*)d_in[9];
    const float* Wp = (const float*)d_in[10];
    const float* bp = (const float*)d_in[11];
    const float* g1 = (const float*)d_in[12];
    const float* b1 = (const float*)d_in[13];
    const float* g2 = (const float*)d_in[14];
    const float* b2 = (const float*)d_in[15];
    const float* W1 = (const float*)d_in[16];
    const float* b1f = (const float*)d_in[17];
    const float* W2 = (const float*)d_in[18];
    const float* b2f = (const float*)d_in[19];

    const int n = in_sizes[0] / 64;   // 50000
    const int E = in_sizes[2] / 32;   // 600000

    // Workspace carve (~90 MB). aggbf (n*128 bf16) ALIASES qx (dead after k_alpha).
    char* p = (char*)d_ws;
    unsigned* qx = (unsigned*)p; p += (size_t)n * 128 * 4;   // q bf16 + wq fused
    unsigned* aggbf = qx;
    unsigned* kbf = (unsigned*)p; p += (size_t)n * 64 * 4;
    unsigned* vbf = (unsigned*)p; p += (size_t)n * 64 * 4;
    int* deg   = (int*)p;   p += (size_t)n * 4;
    p = (char*)(((uintptr_t)p + 15) & ~(uintptr_t)15);
    int* bucket = (int*)p;  p += (size_t)n * 64 * 4;
    float2* exb = (float2*)p; p += (size_t)n * 64 * 8;
    float* Wqt = (float*)p; p += 8192 * 4;
    float* Wkt = (float*)p; p += 8192 * 4;
    float* Wvt = (float*)p; p += 8192 * 4;
    float* Wet = (float*)p; p += 4096 * 4;
    unsigned short* wsW = (unsigned short*)p; p += W_TOT * 2;
    float* bqt = (float*)p; p += 128 * 4;
    float* bkt = (float*)p; p += 128 * 4;
    float* bvt = (float*)p; p += 128 * 4;

    k_pre<<<196, 256, 0, stream>>>(Wq, Wk, Wv, We, Wp, W1, W2, bq, bk, bv,
                                   Wqt, Wkt, Wvt, Wet, wsW, bqt, bkt, bvt,
                                   deg, n);
    k_qkv<<<(n + 31) / 32, 256, 0, stream>>>(x, Wqt, Wkt, Wvt, bqt, bkt, bvt,
                                             g1, b1, We, qx, kbf, vbf, n);
    k_alpha<<<(E + 15) / 16, 256, 0, stream>>>(qx, kbf, ea, ei,
                                               deg, bucket, exb, E, n);
    k_agg<<<(n + 3) / 4, 256, 0, stream>>>(vbf, exb, deg, bucket, ei, ea,
                                           Wet, aggbf, n, E);
    int nb16 = (n + 15) >> 4;
    int blocks = (nb16 + 3) / 4;
    if (blocks > 391) blocks = 391;   // 2 blocks/CU resident, waves grid-stride
    k_post<<<blocks, 256, 0, stream>>>((const unsigned short*)aggbf, wsW,
                                       bp, x, g2, b2, b1f, b2f,
                                       (float*)d_out, n);
}

// Round 4
// 390.052 us; speedup vs baseline: 1.3019x; 1.0182x over previous
//
#include <hip/hip_runtime.h>
#include <math.h>
#include <stdint.h>

// N=50000, E=600000, IN_CH=64, HEADS=2, C=64, HC=128, EDGE_DIM=32
// Layouts:
//   qx  (uint/float mix): [node][128 dwords] = 64 uints bf16-packed q (both heads
//        per channel) followed by 64 floats wq interleaved [d*2+h]. Read once per
//        node by k_attn (node-centric; the per-edge q gather is gone).
//   k/v (bf16 packed uint): [node][c] -> both heads at channel c in one uint
//   Wet (float2): [(d*64+c)] -> (We[d][h0*64+c], We[d][h1*64+c])
//   bucket2 (int2): [tgt][slot] -> (edge id, src) in atomic slot order
//   aggbf (bf16 ushort): [node][cin=c*2+h], 128 bf16/row; own region (no alias).
//   wsW (bf16 ushort): WpT[o][k]@stride152 | W1T[o][k]@88 | W2T[o][k]@88
// All data-derived indices are clamped: no input value can cause OOB.

typedef float f32x4 __attribute__((ext_vector_type(4)));
typedef __bf16 bf16x8 __attribute__((ext_vector_type(8)));
typedef unsigned int u32x4 __attribute__((ext_vector_type(4)));

#define WP_S 152
#define W1_OFF 9728
#define W2_OFF 15360
#define W_TOT 20992
#define H_S 72

__device__ __forceinline__ unsigned pack_bf16(float2 v) {
    unsigned a = __builtin_bit_cast(unsigned, v.x);
    unsigned b = __builtin_bit_cast(unsigned, v.y);
    a = (a + 0x7FFFu + ((a >> 16) & 1u)) >> 16;   // RNE
    b = (b + 0x7FFFu + ((b >> 16) & 1u)) >> 16;
    return a | (b << 16);
}
__device__ __forceinline__ float2 unpack_bf16(unsigned p) {
    float x = __builtin_bit_cast(float, p << 16);
    float y = __builtin_bit_cast(float, p & 0xFFFF0000u);
    return make_float2(x, y);
}
__device__ __forceinline__ unsigned short bf16r(float x) {
    unsigned u = __builtin_bit_cast(unsigned, x);
    return (unsigned short)((u + 0x7FFFu + ((u >> 16) & 1u)) >> 16);
}

__device__ __forceinline__ f32x4 mfma16(bf16x8 a, bf16x8 b, f32x4 c) {
    return __builtin_amdgcn_mfma_f32_16x16x32_bf16(a, b, c, 0, 0, 0);
}
__device__ __forceinline__ bf16x8 frag_ld(const unsigned short* p) {
    return __builtin_bit_cast(bf16x8, *(const u32x4*)p);
}

// deg zero + weight re-layouts (incl. bf16-transposed FFN weights), one launch.
__global__ void k_pre(const float* __restrict__ Wq, const float* __restrict__ Wk,
                      const float* __restrict__ Wv, const float* __restrict__ We,
                      const float* __restrict__ Wp, const float* __restrict__ W1,
                      const float* __restrict__ W2, const float* __restrict__ bq,
                      const float* __restrict__ bk, const float* __restrict__ bv,
                      float* __restrict__ Wqt, float* __restrict__ Wkt,
                      float* __restrict__ Wvt, float* __restrict__ Wet,
                      unsigned short* __restrict__ wsW, float* __restrict__ bqt,
                      float* __restrict__ bkt, float* __restrict__ bvt,
                      int* __restrict__ deg, int n) {
    int idx = blockIdx.x * 256 + threadIdx.x;
    for (int i = idx; i < n; i += gridDim.x * 256) deg[i] = 0;
    if (idx < 8192) {
        // Wq/Wk/Wv: [cin][h*64+c] -> [cin][c*2+h]
        int cin = idx >> 7, j = idx & 127, h = j >> 6, c = j & 63;
        int dst = cin * 128 + c * 2 + h;
        Wqt[dst] = Wq[idx];
        Wkt[dst] = Wk[idx];
        Wvt[dst] = Wv[idx];
        // WpT bf16 [o][k], k=cin=c*2+h -> orig row (k&1)*64 + (k>>1)
        int o = idx >> 7, k = idx & 127;
        wsW[o * WP_S + k] = bf16r(Wp[((k & 1) * 64 + (k >> 1)) * 64 + o]);
    }
    if (idx < 4096) {
        // We: [d][h*64+c] -> [(d*64+c)*2+h]
        int d = idx >> 7, j = idx & 127, h = j >> 6, c = j & 63;
        Wet[(d * 64 + c) * 2 + h] = We[idx];
        // W1T/W2T bf16 [o][k]
        int o = idx >> 6, k = idx & 63;
        wsW[W1_OFF + o * 88 + k] = bf16r(W1[k * 64 + o]);
        wsW[W2_OFF + o * 88 + k] = bf16r(W2[k * 64 + o]);
    }
    if (idx < 128) {
        int h = idx >> 6, c = idx & 63;
        bqt[c * 2 + h] = bq[idx];
        bkt[c * 2 + h] = bk[idx];
        bvt[c * 2 + h] = bv[idx];
    }
}

// Bucket build only: one thread per edge. (alpha itself moved to k_attn.)
__global__ __launch_bounds__(256) void k_bucket(
    const int* __restrict__ ei, int* __restrict__ deg,
    int2* __restrict__ bucket2, int E, int n) {
    int e = blockIdx.x * 256 + threadIdx.x;
    if (e >= E) return;
    int src = ei[e], tgt = ei[E + e];
    src = min(max(src, 0), n - 1);
    tgt = min(max(tgt, 0), n - 1);
    int slot = atomicAdd(&deg[tgt], 1);
    if (slot < 64) bucket2[(size_t)tgt * 64 + slot] = make_int2(e, src);
}

// Fused LN1 + QKV + wq = We^T q. One wave per EIGHT nodes (weight reuse x8).
__global__ __launch_bounds__(256) void k_qkv(
    const float* __restrict__ x,
    const float* __restrict__ Wqt, const float* __restrict__ Wkt, const float* __restrict__ Wvt,
    const float* __restrict__ bqt, const float* __restrict__ bkt, const float* __restrict__ bvt,
    const float* __restrict__ g1, const float* __restrict__ b1,
    const float* __restrict__ We,   // original [d][h*64+c]
    unsigned* __restrict__ qx, unsigned* __restrict__ kbf,
    unsigned* __restrict__ vbf, int n) {
    __shared__ __align__(16) float hT[4][64][8];     // [wave][cin][node]  8 KB
    __shared__ __align__(16) float qs[4][2][8][64];  // [wave][h][node][c] 16 KB
    int wave = threadIdx.x >> 6, lane = threadIdx.x & 63;
    int node0 = blockIdx.x * 32 + wave * 8;
    if (node0 >= n) return;

    // ---- Phase 1: LayerNorm for 8 nodes (8 lanes per node) ----
    int b = lane >> 3, t = lane & 7;
    int nodeb = node0 + b;
    float4 xa = make_float4(0.f, 0.f, 0.f, 0.f), xb = xa;
    if (nodeb < n) {
        const float4* xp = (const float4*)(x + (size_t)nodeb * 64 + t * 8);
        xa = xp[0]; xb = xp[1];
    }
    float s1 = (xa.x + xa.y) + (xa.z + xa.w) + (xb.x + xb.y) + (xb.z + xb.w);
    float s2 = xa.x*xa.x + xa.y*xa.y + xa.z*xa.z + xa.w*xa.w
             + xb.x*xb.x + xb.y*xb.y + xb.z*xb.z + xb.w*xb.w;
#pragma unroll
    for (int m = 1; m < 8; m <<= 1) {
        s1 += __shfl_xor(s1, m);
        s2 += __shfl_xor(s2, m);
    }
    float mean = s1 * 0.015625f;
    float var  = s2 * 0.015625f - mean * mean;
    float rstd = rsqrtf(var + 1e-5f);
    float4 ga = ((const float4*)(g1 + t * 8))[0];
    float4 gb = ((const float4*)(g1 + t * 8))[1];
    float4 ba = ((const float4*)(b1 + t * 8))[0];
    float4 bb = ((const float4*)(b1 + t * 8))[1];
    float hv[8];
    hv[0] = (xa.x - mean) * rstd * ga.x + ba.x;
    hv[1] = (xa.y - mean) * rstd * ga.y + ba.y;
    hv[2] = (xa.z - mean) * rstd * ga.z + ba.z;
    hv[3] = (xa.w - mean) * rstd * ga.w + ba.w;
    hv[4] = (xb.x - mean) * rstd * gb.x + bb.x;
    hv[5] = (xb.y - mean) * rstd * gb.y + bb.y;
    hv[6] = (xb.z - mean) * rstd * gb.z + bb.z;
    hv[7] = (xb.w - mean) * rstd * gb.w + bb.w;
#pragma unroll
    for (int j = 0; j < 8; ++j) hT[wave][t * 8 + j][b] = hv[j];
    // per-wave LDS, wave-lockstep: no barrier needed

    // ---- Phase 2: QKV projection, 8 nodes per weight load ----
    const float2* Wq2 = (const float2*)Wqt;
    const float2* Wk2 = (const float2*)Wkt;
    const float2* Wv2 = (const float2*)Wvt;
    float2 bqv = ((const float2*)bqt)[lane];
    float2 bkv = ((const float2*)bkt)[lane];
    float2 bvv = ((const float2*)bvt)[lane];
    float2 qa[8], ka[8], va[8];
#pragma unroll
    for (int nb = 0; nb < 8; ++nb) { qa[nb] = bqv; ka[nb] = bkv; va[nb] = bvv; }

#pragma unroll 4
    for (int cin = 0; cin < 64; ++cin) {
        float2 w_q = Wq2[cin * 64 + lane];
        float2 w_k = Wk2[cin * 64 + lane];
        float2 w_v = Wv2[cin * 64 + lane];
        const float4* hp = (const float4*)&hT[wave][cin][0];
        float4 h0 = hp[0], h1 = hp[1];   // b128 broadcast
        float hs[8] = {h0.x, h0.y, h0.z, h0.w, h1.x, h1.y, h1.z, h1.w};
#pragma unroll
        for (int nb = 0; nb < 8; ++nb) {
            qa[nb].x += hs[nb] * w_q.x; qa[nb].y += hs[nb] * w_q.y;
            ka[nb].x += hs[nb] * w_k.x; ka[nb].y += hs[nb] * w_k.y;
            va[nb].x += hs[nb] * w_v.x; va[nb].y += hs[nb] * w_v.y;
        }
    }

    // ---- Phase 3: stores + stage q in LDS for phase 4 ----
#pragma unroll
    for (int nb = 0; nb < 8; ++nb) {
        int nd = node0 + nb;
        if (nd < n) {
            qx[(size_t)nd * 128 + lane] = pack_bf16(qa[nb]);
            kbf[(size_t)nd * 64 + lane] = pack_bf16(ka[nb]);
            vbf[(size_t)nd * 64 + lane] = pack_bf16(va[nb]);
        }
        qs[wave][0][nb][lane] = qa[nb].x;
        qs[wave][1][nb][lane] = qa[nb].y;
    }

    // ---- Phase 4: wq = We^T q -> qx[node][64 + d*2 + h], 8 nodes per We load ----
    int hh = lane >> 5, d = lane & 31;
    const float4* Wr = (const float4*)(We + d * 128 + hh * 64);
    float wqa[8] = {0.f, 0.f, 0.f, 0.f, 0.f, 0.f, 0.f, 0.f};
#pragma unroll 4
    for (int c4 = 0; c4 < 16; ++c4) {
        float4 w = Wr[c4];
#pragma unroll
        for (int nb = 0; nb < 8; ++nb) {
            float4 qv = *(const float4*)&qs[wave][hh][nb][c4 * 4];  // broadcast
            wqa[nb] += w.x * qv.x + w.y * qv.y + w.z * qv.z + w.w * qv.w;
        }
    }
#pragma unroll
    for (int nb = 0; nb < 8; ++nb)
        if (node0 + nb < n)
            ((float*)qx)[(size_t)(node0 + nb) * 128 + 64 + d * 2 + hh] = wqa[nb];
}

// Merged attention: alpha + softmax + aggregation, node-centric. One wave/node.
// Per edge (single pass): coalesced k-row + v-row (256 B each) + edge_attr row
// (128 B, read once, feeds BOTH the wq.a logit term and the S accumulator).
// logit = q.k[src] + wq.a via 64-lane butterfly (all lanes end with the total),
// then acc += ex*v, accS += ex*a, den += ex -- no exb buffer, no second pass.
// q/wq read ONCE per node (was a 512 B per-edge gather in the old k_alpha).
__global__ __launch_bounds__(256) void k_attn(
    const unsigned* __restrict__ qx, const unsigned* __restrict__ kbf,
    const unsigned* __restrict__ vbf, const float* __restrict__ edge_attr,
    const int* __restrict__ deg, const int2* __restrict__ bucket2,
    const float* __restrict__ Wet,   // float2 per (d*64+c)
    unsigned* __restrict__ agg, int n, int E) {
    __shared__ __align__(16) float sbuf[4][64];
    int wave = threadIdx.x >> 6, lane = threadIdx.x & 63;
    int node = blockIdx.x * 4 + wave;
    if (node >= n) return;
    int dl = lane & 31, hh = lane >> 5;

    // q channel (both heads) for lane; wq element for (dl,hh).
    float2 q2 = unpack_bf16(qx[(size_t)node * 128 + lane]);
    float wqv = ((const float*)qx)[(size_t)node * 128 + 64 + dl * 2 + hh];

    int dcount = min(deg[node], 64);
    int eid_l = 0, src_l = 0;
    if (lane < dcount) {
        int2 b = bucket2[(size_t)node * 64 + lane];
        eid_l = min(max(b.x, 0), E - 1);
        src_l = min(max(b.y, 0), n - 1);
    }

    float acc0 = 0.f, acc1 = 0.f, accS = 0.f, den0 = 0.f, den1 = 0.f;
    for (int j = 0; j < dcount; ++j) {
        int sj = __shfl(src_l, j);          // uniform j -> readlane broadcast
        int ej = __shfl(eid_l, j);
        unsigned kw = kbf[(size_t)sj * 64 + lane];   // coalesced 256 B row
        unsigned vw = vbf[(size_t)sj * 64 + lane];   // coalesced 256 B row
        float av = edge_attr[(size_t)ej * 32 + dl];  // 128 B, half-wave broadcast
        float2 kk = unpack_bf16(kw);
        float pw = wqv * av;
        float pA = q2.x * kk.x + (hh ? 0.f : pw);
        float pB = q2.y * kk.y + (hh ? pw : 0.f);
#pragma unroll
        for (int m = 1; m < 64; m <<= 1) {   // butterfly: all lanes get totals
            pA += __shfl_xor(pA, m);
            pB += __shfl_xor(pB, m);
        }
        float ex0 = __expf(pA * 0.125f);
        float ex1 = __expf(pB * 0.125f);
        float2 vv = unpack_bf16(vw);
        acc0 += ex0 * vv.x;
        acc1 += ex1 * vv.y;
        accS += (hh ? ex1 : ex0) * av;
        den0 += ex0;
        den1 += ex1;
    }

    // B = We^T S : S to LDS interleaved [d*2+h], then per-lane 64 FMA.
    float* row = sbuf[wave];
    row[dl * 2 + hh] = accS;
    float B0 = 0.f, B1 = 0.f;
    const float2* We2 = (const float2*)Wet;
    const float2* S2 = (const float2*)row;
#pragma unroll
    for (int d = 0; d < 32; ++d) {
        float2 w = We2[d * 64 + lane];
        float2 s = S2[d];   // LDS b64 broadcast
        B0 += w.x * s.x;
        B1 += w.y * s.y;
    }
    float r0 = 1.0f / (den0 + 1e-8f);
    float r1 = 1.0f / (den1 + 1e-8f);
    agg[(size_t)node * 64 + lane] =
        pack_bf16(make_float2((acc0 + B0) * r0, (acc1 + B1) * r1));
}

// Epilogue v4: MFMA. One wave per 16 nodes; 3 GEMMs via mfma_f32_16x16x32_bf16.
// C/D frag: col=lane&15, row=(lane>>4)*4+reg [m89-verified]. A=[M][K] rows,
// B=[N][K] rows (k-contiguous, b128 frags). Weights staged bf16 in LDS (42 KB),
// per-wave h2/h3 transpose buffers (4.6 KB) -> 60.4 KB/block, 2 blocks/CU.
// LN2 via 16-lane shfl_xor on the C-layout. fp32 accum throughout; bf16 only
// on GEMM inputs.
__global__ __launch_bounds__(256) void k_post(
    const unsigned short* __restrict__ aggbf,  // [node][128] bf16, cin=c*2+h
    const unsigned short* __restrict__ wsW,    // packed WpT|W1T|W2T bf16
    const float* __restrict__ bp, const float* __restrict__ x,
    const float* __restrict__ g2, const float* __restrict__ b2,
    const float* __restrict__ b1f, const float* __restrict__ b2f,
    float* __restrict__ out, int n) {
    __shared__ __align__(16) unsigned short sW[W_TOT];        // 41984 B
    __shared__ __align__(16) unsigned short hb[4][2][16 * H_S];  // 18432 B
    int tid = threadIdx.x;
    for (int i = tid; i < W_TOT / 8; i += 256)
        ((u32x4*)sW)[i] = ((const u32x4*)wsW)[i];
    __syncthreads();

    int wave = tid >> 6, lane = tid & 63;
    int cl = lane & 15, kg = lane >> 4;   // col-lane, k-group
    unsigned short* h2 = hb[wave][0];
    unsigned short* h3 = hb[wave][1];

    // hoisted per-column constants: c = t*16 + cl
    float bp_c[4], g2_c[4], b2_c[4], b1_c[4], bf2_c[4];
#pragma unroll
    for (int t = 0; t < 4; ++t) {
        int c = t * 16 + cl;
        bp_c[t] = bp[c];
        g2_c[t] = g2[c];
        b2_c[t] = b2[c];
        b1_c[t] = b1f[c];
        bf2_c[t] = b2f[c];
    }

    int wid = blockIdx.x * 4 + wave;
    int nbatch = (n + 15) >> 4;
    int nwaves = gridDim.x * 4;
    for (int bt = wid; bt < nbatch; bt += nwaves) {
        int node0 = bt * 16;

        // ---- GEMM1: acc1 = agg(16x128,bf16) @ Wp + bp + x ----
        f32x4 acc1[4];
#pragma unroll
        for (int t = 0; t < 4; ++t) acc1[t] = (f32x4){0.f, 0.f, 0.f, 0.f};
        int arow = min(node0 + cl, n - 1);
#pragma unroll
        for (int s = 0; s < 4; ++s) {
            bf16x8 af = frag_ld(aggbf + (size_t)arow * 128 + s * 32 + kg * 8);
#pragma unroll
            for (int t = 0; t < 4; ++t) {
                bf16x8 bf = frag_ld(sW + (t * 16 + cl) * WP_S + s * 32 + kg * 8);
                acc1[t] = mfma16(af, bf, acc1[t]);
            }
        }
#pragma unroll
        for (int t = 0; t < 4; ++t) {
#pragma unroll
            for (int j = 0; j < 4; ++j) {
                int nd = min(node0 + kg * 4 + j, n - 1);
                acc1[t][j] += bp_c[t] + x[(size_t)nd * 64 + t * 16 + cl];
            }
        }

        // ---- LN2 over 64 channels of rows r = kg*4+j ----
        float mean[4], rstd[4];
#pragma unroll
        for (int j = 0; j < 4; ++j) {
            float s1 = acc1[0][j] + acc1[1][j] + acc1[2][j] + acc1[3][j];
            float s2 = acc1[0][j] * acc1[0][j] + acc1[1][j] * acc1[1][j]
                     + acc1[2][j] * acc1[2][j] + acc1[3][j] * acc1[3][j];
#pragma unroll
            for (int m = 1; m < 16; m <<= 1) {
                s1 += __shfl_xor(s1, m);
                s2 += __shfl_xor(s2, m);
            }
            mean[j] = s1 * 0.015625f;
            float var = s2 * 0.015625f - mean[j] * mean[j];
            rstd[j] = rsqrtf(var + 1e-5f);
        }
#pragma unroll
        for (int t = 0; t < 4; ++t)
#pragma unroll
            for (int j = 0; j < 4; ++j) {
                float v = (acc1[t][j] - mean[j]) * rstd[j] * g2_c[t] + b2_c[t];
                h2[(kg * 4 + j) * H_S + t * 16 + cl] = bf16r(v);
            }
        asm volatile("s_waitcnt lgkmcnt(0)" ::: "memory");

        // ---- GEMM2: f = h2(16x64) @ W1 + b1; gelu -> h3 ----
        f32x4 acc2[4];
#pragma unroll
        for (int t = 0; t < 4; ++t)
            acc2[t] = (f32x4){b1_c[t], b1_c[t], b1_c[t], b1_c[t]};
#pragma unroll
        for (int s = 0; s < 2; ++s) {
            bf16x8 af = frag_ld(h2 + cl * H_S + s * 32 + kg * 8);
#pragma unroll
            for (int t = 0; t < 4; ++t) {
                bf16x8 bf = frag_ld(sW + W1_OFF + (t * 16 + cl) * 88 + s * 32 + kg * 8);
                acc2[t] = mfma16(af, bf, acc2[t]);
            }
        }
#pragma unroll
        for (int t = 0; t < 4; ++t)
#pragma unroll
            for (int j = 0; j < 4; ++j) {
                float v = acc2[t][j];
                v = 0.5f * v * (1.0f + erff(v * 0.70710678118654752f));
                h3[(kg * 4 + j) * H_S + t * 16 + cl] = bf16r(v);
            }
        asm volatile("s_waitcnt lgkmcnt(0)" ::: "memory");

        // ---- GEMM3: y = gelu @ W2 + b2f + acc1 (residual 2) ----
        f32x4 acc3[4];
#pragma unroll
        for (int t = 0; t < 4; ++t) {
            acc3[t] = acc1[t];
#pragma unroll
            for (int j = 0; j < 4; ++j) acc3[t][j] += bf2_c[t];
        }
#pragma unroll
        for (int s = 0; s < 2; ++s) {
            bf16x8 af = frag_ld(h3 + cl * H_S + s * 32 + kg * 8);
#pragma unroll
            for (int t = 0; t < 4; ++t) {
                bf16x8 bf = frag_ld(sW + W2_OFF + (t * 16 + cl) * 88 + s * 32 + kg * 8);
                acc3[t] = mfma16(af, bf, acc3[t]);
            }
        }
#pragma unroll
        for (int t = 0; t < 4; ++t)
#pragma unroll
            for (int j = 0; j < 4; ++j) {
                int r = node0 + kg * 4 + j;
                if (r < n) out[(size_t)r * 64 + t * 16 + cl] = acc3[t][j];
            }
    }
}

extern "C" void kernel_launch(void* const* d_in, const int* in_sizes, int n_in,
                              void* d_out, int out_size, void* d_ws, size_t ws_size,
                              hipStream_t stream) {
    const float* x  = (const float*)d_in[0];
    const int*   ei = (const int*)d_in[1];
    const float* ea = (const float*)d_in[2];
    const float* Wq = (const float*)d_in[3];
    const float* bq = (const float*)d_in[4];
    const float* Wk = (const float*)d_in[5];
    const float* bk = (const float*)d_in[6];
    const float* Wv = (const float*)d_in[7];
    const float* bv = (const float*)d_in[8];
    const float* We = (const float*)d_in[9];
    const float* Wp = (const float*)d_in[10];
    const float* bp = (const float*)d_in[11];
    const float* g1 = (const float*)d_in[12];
    const float* b1 = (const float*)d_in[13];
    const float* g2 = (const float*)d_in[14];
    const float* b2 = (const float*)d_in[15];
    const float* W1 = (const float*)d_in[16];
    const float* b1f = (const float*)d_in[17];
    const float* W2 = (const float*)d_in[18];
    const float* b2f = (const float*)d_in[19];

    const int n = in_sizes[0] / 64;   // 50000
    const int E = in_sizes[2] / 32;   // 600000

    // Workspace carve (~90 MB). aggbf now a SEPARATE region (k_attn reads qx
    // and writes agg in the same kernel -> no aliasing allowed).
    char* p = (char*)d_ws;
    unsigned* qx = (unsigned*)p; p += (size_t)n * 128 * 4;   // q bf16 + wq fused
    unsigned* kbf = (unsigned*)p; p += (size_t)n * 64 * 4;
    unsigned* vbf = (unsigned*)p; p += (size_t)n * 64 * 4;
    int* deg   = (int*)p;   p += (size_t)n * 4;
    p = (char*)(((uintptr_t)p + 15) & ~(uintptr_t)15);
    int2* bucket2 = (int2*)p; p += (size_t)n * 64 * 8;
    unsigned* aggbf = (unsigned*)p; p += (size_t)n * 64 * 4;
    float* Wqt = (float*)p; p += 8192 * 4;
    float* Wkt = (float*)p; p += 8192 * 4;
    float* Wvt = (float*)p; p += 8192 * 4;
    float* Wet = (float*)p; p += 4096 * 4;
    unsigned short* wsW = (unsigned short*)p; p += W_TOT * 2;
    float* bqt = (float*)p; p += 128 * 4;
    float* bkt = (float*)p; p += 128 * 4;
    float* bvt = (float*)p; p += 128 * 4;

    k_pre<<<196, 256, 0, stream>>>(Wq, Wk, Wv, We, Wp, W1, W2, bq, bk, bv,
                                   Wqt, Wkt, Wvt, Wet, wsW, bqt, bkt, bvt,
                                   deg, n);
    k_bucket<<<(E + 255) / 256, 256, 0, stream>>>(ei, deg, bucket2, E, n);
    k_qkv<<<(n + 31) / 32, 256, 0, stream>>>(x, Wqt, Wkt, Wvt, bqt, bkt, bvt,
                                             g1, b1, We, qx, kbf, vbf, n);
    k_attn<<<(n + 3) / 4, 256, 0, stream>>>(qx, kbf, vbf, ea, deg, bucket2,
                                            Wet, aggbf, n, E);
    int nb16 = (n + 15) >> 4;
    int blocks = (nb16 + 3) / 4;
    if (blocks > 391) blocks = 391;   // 2 blocks/CU resident, waves grid-stride
    k_post<<<blocks, 256, 0, stream>>>((const unsigned short*)aggbf, wsW,
                                       bp, x, g2, b2, b1f, b2f,
                                       (float*)d_out, n);
}

// Round 5
// 364.321 us; speedup vs baseline: 1.3938x; 1.0706x over previous
//
#include <hip/hip_runtime.h>
#include <math.h>
#include <stdint.h>

// N=50000, E=600000, IN_CH=64, HEADS=2, C=64, HC=128, EDGE_DIM=32
// Layouts:
//   qx  (uint/float mix): [node][128 dwords] = 64 uints bf16-packed q (both heads
//        per channel) followed by 64 floats wq interleaved [d*2+h]. Read once per
//        node by k_attn (node-centric; staged in LDS for the edge loop).
//   k/v (bf16 packed uint): [node][c] -> both heads at channel c in one uint
//   Wet (float2): [(d*64+c)] -> (We[d][h0*64+c], We[d][h1*64+c])
//   bucket2 (int2): [tgt][slot] -> (edge id, src) in atomic slot order
//   aggbf (bf16 ushort): [node][cin=c*2+h], 128 bf16/row; own region (no alias).
//   wsW (bf16 ushort): WpT[o][k]@stride152 | W1T[o][k]@88 | W2T[o][k]@88
// All data-derived indices are clamped: no input value can cause OOB.

typedef float f32x4 __attribute__((ext_vector_type(4)));
typedef __bf16 bf16x8 __attribute__((ext_vector_type(8)));
typedef unsigned int u32x4 __attribute__((ext_vector_type(4)));

#define WP_S 152
#define W1_OFF 9728
#define W2_OFF 15360
#define W_TOT 20992
#define H_S 72

__device__ __forceinline__ unsigned pack_bf16(float2 v) {
    unsigned a = __builtin_bit_cast(unsigned, v.x);
    unsigned b = __builtin_bit_cast(unsigned, v.y);
    a = (a + 0x7FFFu + ((a >> 16) & 1u)) >> 16;   // RNE
    b = (b + 0x7FFFu + ((b >> 16) & 1u)) >> 16;
    return a | (b << 16);
}
__device__ __forceinline__ float2 unpack_bf16(unsigned p) {
    float x = __builtin_bit_cast(float, p << 16);
    float y = __builtin_bit_cast(float, p & 0xFFFF0000u);
    return make_float2(x, y);
}
__device__ __forceinline__ unsigned short bf16r(float x) {
    unsigned u = __builtin_bit_cast(unsigned, x);
    return (unsigned short)((u + 0x7FFFu + ((u >> 16) & 1u)) >> 16);
}

__device__ __forceinline__ f32x4 mfma16(bf16x8 a, bf16x8 b, f32x4 c) {
    return __builtin_amdgcn_mfma_f32_16x16x32_bf16(a, b, c, 0, 0, 0);
}
__device__ __forceinline__ bf16x8 frag_ld(const unsigned short* p) {
    return __builtin_bit_cast(bf16x8, *(const u32x4*)p);
}

// deg zero + weight re-layouts (incl. bf16-transposed FFN weights), one launch.
__global__ void k_pre(const float* __restrict__ Wq, const float* __restrict__ Wk,
                      const float* __restrict__ Wv, const float* __restrict__ We,
                      const float* __restrict__ Wp, const float* __restrict__ W1,
                      const float* __restrict__ W2, const float* __restrict__ bq,
                      const float* __restrict__ bk, const float* __restrict__ bv,
                      float* __restrict__ Wqt, float* __restrict__ Wkt,
                      float* __restrict__ Wvt, float* __restrict__ Wet,
                      unsigned short* __restrict__ wsW, float* __restrict__ bqt,
                      float* __restrict__ bkt, float* __restrict__ bvt,
                      int* __restrict__ deg, int n) {
    int idx = blockIdx.x * 256 + threadIdx.x;
    for (int i = idx; i < n; i += gridDim.x * 256) deg[i] = 0;
    if (idx < 8192) {
        // Wq/Wk/Wv: [cin][h*64+c] -> [cin][c*2+h]
        int cin = idx >> 7, j = idx & 127, h = j >> 6, c = j & 63;
        int dst = cin * 128 + c * 2 + h;
        Wqt[dst] = Wq[idx];
        Wkt[dst] = Wk[idx];
        Wvt[dst] = Wv[idx];
        // WpT bf16 [o][k], k=cin=c*2+h -> orig row (k&1)*64 + (k>>1)
        int o = idx >> 7, k = idx & 127;
        wsW[o * WP_S + k] = bf16r(Wp[((k & 1) * 64 + (k >> 1)) * 64 + o]);
    }
    if (idx < 4096) {
        // We: [d][h*64+c] -> [(d*64+c)*2+h]
        int d = idx >> 7, j = idx & 127, h = j >> 6, c = j & 63;
        Wet[(d * 64 + c) * 2 + h] = We[idx];
        // W1T/W2T bf16 [o][k]
        int o = idx >> 6, k = idx & 63;
        wsW[W1_OFF + o * 88 + k] = bf16r(W1[k * 64 + o]);
        wsW[W2_OFF + o * 88 + k] = bf16r(W2[k * 64 + o]);
    }
    if (idx < 128) {
        int h = idx >> 6, c = idx & 63;
        bqt[c * 2 + h] = bq[idx];
        bkt[c * 2 + h] = bk[idx];
        bvt[c * 2 + h] = bv[idx];
    }
}

// Bucket build only: one thread per edge.
__global__ __launch_bounds__(256) void k_bucket(
    const int* __restrict__ ei, int* __restrict__ deg,
    int2* __restrict__ bucket2, int E, int n) {
    int e = blockIdx.x * 256 + threadIdx.x;
    if (e >= E) return;
    int src = ei[e], tgt = ei[E + e];
    src = min(max(src, 0), n - 1);
    tgt = min(max(tgt, 0), n - 1);
    int slot = atomicAdd(&deg[tgt], 1);
    if (slot < 64) bucket2[(size_t)tgt * 64 + slot] = make_int2(e, src);
}

// Fused LN1 + QKV + wq = We^T q. One wave per EIGHT nodes (weight reuse x8).
__global__ __launch_bounds__(256) void k_qkv(
    const float* __restrict__ x,
    const float* __restrict__ Wqt, const float* __restrict__ Wkt, const float* __restrict__ Wvt,
    const float* __restrict__ bqt, const float* __restrict__ bkt, const float* __restrict__ bvt,
    const float* __restrict__ g1, const float* __restrict__ b1,
    const float* __restrict__ We,   // original [d][h*64+c]
    unsigned* __restrict__ qx, unsigned* __restrict__ kbf,
    unsigned* __restrict__ vbf, int n) {
    __shared__ __align__(16) float hT[4][64][8];     // [wave][cin][node]  8 KB
    __shared__ __align__(16) float qs[4][2][8][64];  // [wave][h][node][c] 16 KB
    int wave = threadIdx.x >> 6, lane = threadIdx.x & 63;
    int node0 = blockIdx.x * 32 + wave * 8;
    if (node0 >= n) return;

    // ---- Phase 1: LayerNorm for 8 nodes (8 lanes per node) ----
    int b = lane >> 3, t = lane & 7;
    int nodeb = node0 + b;
    float4 xa = make_float4(0.f, 0.f, 0.f, 0.f), xb = xa;
    if (nodeb < n) {
        const float4* xp = (const float4*)(x + (size_t)nodeb * 64 + t * 8);
        xa = xp[0]; xb = xp[1];
    }
    float s1 = (xa.x + xa.y) + (xa.z + xa.w) + (xb.x + xb.y) + (xb.z + xb.w);
    float s2 = xa.x*xa.x + xa.y*xa.y + xa.z*xa.z + xa.w*xa.w
             + xb.x*xb.x + xb.y*xb.y + xb.z*xb.z + xb.w*xb.w;
#pragma unroll
    for (int m = 1; m < 8; m <<= 1) {
        s1 += __shfl_xor(s1, m);
        s2 += __shfl_xor(s2, m);
    }
    float mean = s1 * 0.015625f;
    float var  = s2 * 0.015625f - mean * mean;
    float rstd = rsqrtf(var + 1e-5f);
    float4 ga = ((const float4*)(g1 + t * 8))[0];
    float4 gb = ((const float4*)(g1 + t * 8))[1];
    float4 ba = ((const float4*)(b1 + t * 8))[0];
    float4 bb = ((const float4*)(b1 + t * 8))[1];
    float hv[8];
    hv[0] = (xa.x - mean) * rstd * ga.x + ba.x;
    hv[1] = (xa.y - mean) * rstd * ga.y + ba.y;
    hv[2] = (xa.z - mean) * rstd * ga.z + ba.z;
    hv[3] = (xa.w - mean) * rstd * ga.w + ba.w;
    hv[4] = (xb.x - mean) * rstd * gb.x + bb.x;
    hv[5] = (xb.y - mean) * rstd * gb.y + bb.y;
    hv[6] = (xb.z - mean) * rstd * gb.z + bb.z;
    hv[7] = (xb.w - mean) * rstd * gb.w + bb.w;
#pragma unroll
    for (int j = 0; j < 8; ++j) hT[wave][t * 8 + j][b] = hv[j];
    // per-wave LDS, wave-lockstep: no barrier needed

    // ---- Phase 2: QKV projection, 8 nodes per weight load ----
    const float2* Wq2 = (const float2*)Wqt;
    const float2* Wk2 = (const float2*)Wkt;
    const float2* Wv2 = (const float2*)Wvt;
    float2 bqv = ((const float2*)bqt)[lane];
    float2 bkv = ((const float2*)bkt)[lane];
    float2 bvv = ((const float2*)bvt)[lane];
    float2 qa[8], ka[8], va[8];
#pragma unroll
    for (int nb = 0; nb < 8; ++nb) { qa[nb] = bqv; ka[nb] = bkv; va[nb] = bvv; }

#pragma unroll 4
    for (int cin = 0; cin < 64; ++cin) {
        float2 w_q = Wq2[cin * 64 + lane];
        float2 w_k = Wk2[cin * 64 + lane];
        float2 w_v = Wv2[cin * 64 + lane];
        const float4* hp = (const float4*)&hT[wave][cin][0];
        float4 h0 = hp[0], h1 = hp[1];   // b128 broadcast
        float hs[8] = {h0.x, h0.y, h0.z, h0.w, h1.x, h1.y, h1.z, h1.w};
#pragma unroll
        for (int nb = 0; nb < 8; ++nb) {
            qa[nb].x += hs[nb] * w_q.x; qa[nb].y += hs[nb] * w_q.y;
            ka[nb].x += hs[nb] * w_k.x; ka[nb].y += hs[nb] * w_k.y;
            va[nb].x += hs[nb] * w_v.x; va[nb].y += hs[nb] * w_v.y;
        }
    }

    // ---- Phase 3: stores + stage q in LDS for phase 4 ----
#pragma unroll
    for (int nb = 0; nb < 8; ++nb) {
        int nd = node0 + nb;
        if (nd < n) {
            qx[(size_t)nd * 128 + lane] = pack_bf16(qa[nb]);
            kbf[(size_t)nd * 64 + lane] = pack_bf16(ka[nb]);
            vbf[(size_t)nd * 64 + lane] = pack_bf16(va[nb]);
        }
        qs[wave][0][nb][lane] = qa[nb].x;
        qs[wave][1][nb][lane] = qa[nb].y;
    }

    // ---- Phase 4: wq = We^T q -> qx[node][64 + d*2 + h], 8 nodes per We load ----
    int hh = lane >> 5, d = lane & 31;
    const float4* Wr = (const float4*)(We + d * 128 + hh * 64);
    float wqa[8] = {0.f, 0.f, 0.f, 0.f, 0.f, 0.f, 0.f, 0.f};
#pragma unroll 4
    for (int c4 = 0; c4 < 16; ++c4) {
        float4 w = Wr[c4];
#pragma unroll
        for (int nb = 0; nb < 8; ++nb) {
            float4 qv = *(const float4*)&qs[wave][hh][nb][c4 * 4];  // broadcast
            wqa[nb] += w.x * qv.x + w.y * qv.y + w.z * qv.z + w.w * qv.w;
        }
    }
#pragma unroll
    for (int nb = 0; nb < 8; ++nb)
        if (node0 + nb < n)
            ((float*)qx)[(size_t)(node0 + nb) * 128 + 64 + d * 2 + hh] = wqa[nb];
}

// Merged attention v2: node-centric but EDGE-PARALLEL inside the wave.
// 4 edges per iteration, 16 lanes per edge (butterfly masks 1..8 only -> the
// per-edge serial chain is 4 shfl steps shared by 4 edges, ~5x less than v1's
// 6-step full-wave butterfly per single edge). q/wq staged once per node in
// LDS; edge_attr read once (feeds logit wq.a term AND the S accumulator);
// group-private partial sums, single cross-group reduce (masks 16,32) per node.
__global__ __launch_bounds__(256) void k_attn(
    const unsigned* __restrict__ qx, const unsigned* __restrict__ kbf,
    const unsigned* __restrict__ vbf, const float* __restrict__ edge_attr,
    const int* __restrict__ deg, const int2* __restrict__ bucket2,
    const float* __restrict__ Wet,   // float2 per (d*64+c)
    unsigned* __restrict__ agg, int n, int E) {
    __shared__ __align__(16) unsigned sq[4][64];   // q packed, per wave
    __shared__ __align__(16) float swq[4][64];     // wq interleaved [d*2+h]
    __shared__ __align__(16) float srow[4][64];    // S for We^T S GEMV
    __shared__ __align__(16) float2 sv[4][64];     // acc channel relayout
    int wave = threadIdx.x >> 6, lane = threadIdx.x & 63;
    int node = blockIdx.x * 4 + wave;
    if (node >= n) return;
    int sub = lane >> 4, l = lane & 15;

    // Stage q row (256 B) + wq row (256 B) once per node, coalesced.
    sq[wave][lane] = qx[(size_t)node * 128 + lane];
    swq[wave][lane] = ((const float*)qx)[(size_t)node * 128 + 64 + lane];

    int dcount = min(deg[node], 64);
    int eid_l = 0, src_l = 0;
    if (lane < dcount) {
        int2 b = bucket2[(size_t)node * 64 + lane];
        eid_l = min(max(b.x, 0), E - 1);
        src_l = min(max(b.y, 0), n - 1);
    }

    // Per-lane q fragment (channels 4l..4l+3) and wq fragment (dims 2l,2l+1).
    uint4 qq = *(const uint4*)&sq[wave][l * 4];
    float4 w4 = *(const float4*)&swq[wave][l * 4];
    float2 q0 = unpack_bf16(qq.x), q1 = unpack_bf16(qq.y),
           q2 = unpack_bf16(qq.z), q3 = unpack_bf16(qq.w);

    float accA[4] = {0.f, 0.f, 0.f, 0.f}, accB[4] = {0.f, 0.f, 0.f, 0.f};
    float aS0 = 0.f, aS1 = 0.f, bS0 = 0.f, bS1 = 0.f;
    float den0 = 0.f, den1 = 0.f;

    for (int i = 0; i < dcount; i += 4) {
        int j = i + sub;
        bool valid = j < dcount;
        int jj = j & 63;                      // wraps to initialized lanes
        int ej = __shfl(eid_l, jj);
        int sj = __shfl(src_l, jj);
        uint4 kk = ((const uint4*)kbf)[(size_t)sj * 16 + l];  // 256 B/group
        uint4 vv = ((const uint4*)vbf)[(size_t)sj * 16 + l];  // 256 B/group
        float2 a2 = ((const float2*)edge_attr)[(size_t)ej * 16 + l];
        float2 k0 = unpack_bf16(kk.x), k1 = unpack_bf16(kk.y),
               k2 = unpack_bf16(kk.z), k3 = unpack_bf16(kk.w);
        float r0 = q0.x * k0.x + q1.x * k1.x + q2.x * k2.x + q3.x * k3.x
                 + w4.x * a2.x + w4.z * a2.y;
        float r1 = q0.y * k0.y + q1.y * k1.y + q2.y * k2.y + q3.y * k3.y
                 + w4.y * a2.x + w4.w * a2.y;
#pragma unroll
        for (int m = 1; m < 16; m <<= 1) {    // 4 steps, stays in 16-lane group
            r0 += __shfl_xor(r0, m);
            r1 += __shfl_xor(r1, m);
        }
        float ex0 = valid ? __expf(r0 * 0.125f) : 0.f;
        float ex1 = valid ? __expf(r1 * 0.125f) : 0.f;
        float2 v0 = unpack_bf16(vv.x), v1 = unpack_bf16(vv.y),
               v2 = unpack_bf16(vv.z), v3 = unpack_bf16(vv.w);
        accA[0] += ex0 * v0.x; accB[0] += ex1 * v0.y;
        accA[1] += ex0 * v1.x; accB[1] += ex1 * v1.y;
        accA[2] += ex0 * v2.x; accB[2] += ex1 * v2.y;
        accA[3] += ex0 * v3.x; accB[3] += ex1 * v3.y;
        aS0 += ex0 * a2.x; aS1 += ex1 * a2.x;
        bS0 += ex0 * a2.y; bS1 += ex1 * a2.y;
        den0 += ex0; den1 += ex1;
    }

    // Single cross-group reduce per node (lanes l, l+16, l+32, l+48).
#pragma unroll
    for (int m = 16; m < 64; m <<= 1) {
#pragma unroll
        for (int j = 0; j < 4; ++j) {
            accA[j] += __shfl_xor(accA[j], m);
            accB[j] += __shfl_xor(accB[j], m);
        }
        aS0 += __shfl_xor(aS0, m); aS1 += __shfl_xor(aS1, m);
        bS0 += __shfl_xor(bS0, m); bS1 += __shfl_xor(bS1, m);
        den0 += __shfl_xor(den0, m); den1 += __shfl_xor(den1, m);
    }

    // Relayout to channel-per-lane via LDS (wave-local, lockstep).
    if (sub == 0) {
        srow[wave][4 * l + 0] = aS0;   // S[d=2l][h0]
        srow[wave][4 * l + 1] = aS1;   // S[d=2l][h1]
        srow[wave][4 * l + 2] = bS0;   // S[d=2l+1][h0]
        srow[wave][4 * l + 3] = bS1;
        sv[wave][4 * l + 0] = make_float2(accA[0], accB[0]);
        sv[wave][4 * l + 1] = make_float2(accA[1], accB[1]);
        sv[wave][4 * l + 2] = make_float2(accA[2], accB[2]);
        sv[wave][4 * l + 3] = make_float2(accA[3], accB[3]);
    }

    // B = We^T S : per-lane (channel=lane) 32 float2 FMAs, S via LDS broadcast.
    float B0 = 0.f, B1 = 0.f;
    const float2* We2 = (const float2*)Wet;
    const float2* S2 = (const float2*)srow[wave];
#pragma unroll
    for (int d = 0; d < 32; ++d) {
        float2 w = We2[d * 64 + lane];
        float2 s = S2[d];
        B0 += w.x * s.x;
        B1 += w.y * s.y;
    }
    float2 av2 = sv[wave][lane];
    float r0 = 1.0f / (den0 + 1e-8f);
    float r1 = 1.0f / (den1 + 1e-8f);
    agg[(size_t)node * 64 + lane] =
        pack_bf16(make_float2((av2.x + B0) * r0, (av2.y + B1) * r1));
}

// Epilogue v4: MFMA. One wave per 16 nodes; 3 GEMMs via mfma_f32_16x16x32_bf16.
__global__ __launch_bounds__(256) void k_post(
    const unsigned short* __restrict__ aggbf,  // [node][128] bf16, cin=c*2+h
    const unsigned short* __restrict__ wsW,    // packed WpT|W1T|W2T bf16
    const float* __restrict__ bp, const float* __restrict__ x,
    const float* __restrict__ g2, const float* __restrict__ b2,
    const float* __restrict__ b1f, const float* __restrict__ b2f,
    float* __restrict__ out, int n) {
    __shared__ __align__(16) unsigned short sW[W_TOT];        // 41984 B
    __shared__ __align__(16) unsigned short hb[4][2][16 * H_S];  // 18432 B
    int tid = threadIdx.x;
    for (int i = tid; i < W_TOT / 8; i += 256)
        ((u32x4*)sW)[i] = ((const u32x4*)wsW)[i];
    __syncthreads();

    int wave = tid >> 6, lane = tid & 63;
    int cl = lane & 15, kg = lane >> 4;   // col-lane, k-group
    unsigned short* h2 = hb[wave][0];
    unsigned short* h3 = hb[wave][1];

    // hoisted per-column constants: c = t*16 + cl
    float bp_c[4], g2_c[4], b2_c[4], b1_c[4], bf2_c[4];
#pragma unroll
    for (int t = 0; t < 4; ++t) {
        int c = t * 16 + cl;
        bp_c[t] = bp[c];
        g2_c[t] = g2[c];
        b2_c[t] = b2[c];
        b1_c[t] = b1f[c];
        bf2_c[t] = b2f[c];
    }

    int wid = blockIdx.x * 4 + wave;
    int nbatch = (n + 15) >> 4;
    int nwaves = gridDim.x * 4;
    for (int bt = wid; bt < nbatch; bt += nwaves) {
        int node0 = bt * 16;

        // ---- GEMM1: acc1 = agg(16x128,bf16) @ Wp + bp + x ----
        f32x4 acc1[4];
#pragma unroll
        for (int t = 0; t < 4; ++t) acc1[t] = (f32x4){0.f, 0.f, 0.f, 0.f};
        int arow = min(node0 + cl, n - 1);
#pragma unroll
        for (int s = 0; s < 4; ++s) {
            bf16x8 af = frag_ld(aggbf + (size_t)arow * 128 + s * 32 + kg * 8);
#pragma unroll
            for (int t = 0; t < 4; ++t) {
                bf16x8 bf = frag_ld(sW + (t * 16 + cl) * WP_S + s * 32 + kg * 8);
                acc1[t] = mfma16(af, bf, acc1[t]);
            }
        }
#pragma unroll
        for (int t = 0; t < 4; ++t) {
#pragma unroll
            for (int j = 0; j < 4; ++j) {
                int nd = min(node0 + kg * 4 + j, n - 1);
                acc1[t][j] += bp_c[t] + x[(size_t)nd * 64 + t * 16 + cl];
            }
        }

        // ---- LN2 over 64 channels of rows r = kg*4+j ----
        float mean[4], rstd[4];
#pragma unroll
        for (int j = 0; j < 4; ++j) {
            float s1 = acc1[0][j] + acc1[1][j] + acc1[2][j] + acc1[3][j];
            float s2 = acc1[0][j] * acc1[0][j] + acc1[1][j] * acc1[1][j]
                     + acc1[2][j] * acc1[2][j] + acc1[3][j] * acc1[3][j];
#pragma unroll
            for (int m = 1; m < 16; m <<= 1) {
                s1 += __shfl_xor(s1, m);
                s2 += __shfl_xor(s2, m);
            }
            mean[j] = s1 * 0.015625f;
            float var = s2 * 0.015625f - mean[j] * mean[j];
            rstd[j] = rsqrtf(var + 1e-5f);
        }
#pragma unroll
        for (int t = 0; t < 4; ++t)
#pragma unroll
            for (int j = 0; j < 4; ++j) {
                float v = (acc1[t][j] - mean[j]) * rstd[j] * g2_c[t] + b2_c[t];
                h2[(kg * 4 + j) * H_S + t * 16 + cl] = bf16r(v);
            }
        asm volatile("s_waitcnt lgkmcnt(0)" ::: "memory");

        // ---- GEMM2: f = h2(16x64) @ W1 + b1; gelu -> h3 ----
        f32x4 acc2[4];
#pragma unroll
        for (int t = 0; t < 4; ++t)
            acc2[t] = (f32x4){b1_c[t], b1_c[t], b1_c[t], b1_c[t]};
#pragma unroll
        for (int s = 0; s < 2; ++s) {
            bf16x8 af = frag_ld(h2 + cl * H_S + s * 32 + kg * 8);
#pragma unroll
            for (int t = 0; t < 4; ++t) {
                bf16x8 bf = frag_ld(sW + W1_OFF + (t * 16 + cl) * 88 + s * 32 + kg * 8);
                acc2[t] = mfma16(af, bf, acc2[t]);
            }
        }
#pragma unroll
        for (int t = 0; t < 4; ++t)
#pragma unroll
            for (int j = 0; j < 4; ++j) {
                float v = acc2[t][j];
                v = 0.5f * v * (1.0f + erff(v * 0.70710678118654752f));
                h3[(kg * 4 + j) * H_S + t * 16 + cl] = bf16r(v);
            }
        asm volatile("s_waitcnt lgkmcnt(0)" ::: "memory");

        // ---- GEMM3: y = gelu @ W2 + b2f + acc1 (residual 2) ----
        f32x4 acc3[4];
#pragma unroll
        for (int t = 0; t < 4; ++t) {
            acc3[t] = acc1[t];
#pragma unroll
            for (int j = 0; j < 4; ++j) acc3[t][j] += bf2_c[t];
        }
#pragma unroll
        for (int s = 0; s < 2; ++s) {
            bf16x8 af = frag_ld(h3 + cl * H_S + s * 32 + kg * 8);
#pragma unroll
            for (int t = 0; t < 4; ++t) {
                bf16x8 bf = frag_ld(sW + W2_OFF + (t * 16 + cl) * 88 + s * 32 + kg * 8);
                acc3[t] = mfma16(af, bf, acc3[t]);
            }
        }
#pragma unroll
        for (int t = 0; t < 4; ++t)
#pragma unroll
            for (int j = 0; j < 4; ++j) {
                int r = node0 + kg * 4 + j;
                if (r < n) out[(size_t)r * 64 + t * 16 + cl] = acc3[t][j];
            }
    }
}

extern "C" void kernel_launch(void* const* d_in, const int* in_sizes, int n_in,
                              void* d_out, int out_size, void* d_ws, size_t ws_size,
                              hipStream_t stream) {
    const float* x  = (const float*)d_in[0];
    const int*   ei = (const int*)d_in[1];
    const float* ea = (const float*)d_in[2];
    const float* Wq = (const float*)d_in[3];
    const float* bq = (const float*)d_in[4];
    const float* Wk = (const float*)d_in[5];
    const float* bk = (const float*)d_in[6];
    const float* Wv = (const float*)d_in[7];
    const float* bv = (const float*)d_in[8];
    const float* We = (const float*)d_in[9];
    const float* Wp = (const float*)d_in[10];
    const float* bp = (const float*)d_in[11];
    const float* g1 = (const float*)d_in[12];
    const float* b1 = (const float*)d_in[13];
    const float* g2 = (const float*)d_in[14];
    const float* b2 = (const float*)d_in[15];
    const float* W1 = (const float*)d_in[16];
    const float* b1f = (const float*)d_in[17];
    const float* W2 = (const float*)d_in[18];
    const float* b2f = (const float*)d_in[19];

    const int n = in_sizes[0] / 64;   // 50000
    const int E = in_sizes[2] / 32;   // 600000

    // Workspace carve (~90 MB). aggbf a SEPARATE region (k_attn reads qx
    // and writes agg in the same kernel -> no aliasing allowed).
    char* p = (char*)d_ws;
    unsigned* qx = (unsigned*)p; p += (size_t)n * 128 * 4;   // q bf16 + wq fused
    unsigned* kbf = (unsigned*)p; p += (size_t)n * 64 * 4;
    unsigned* vbf = (unsigned*)p; p += (size_t)n * 64 * 4;
    int* deg   = (int*)p;   p += (size_t)n * 4;
    p = (char*)(((uintptr_t)p + 15) & ~(uintptr_t)15);
    int2* bucket2 = (int2*)p; p += (size_t)n * 64 * 8;
    unsigned* aggbf = (unsigned*)p; p += (size_t)n * 64 * 4;
    float* Wqt = (float*)p; p += 8192 * 4;
    float* Wkt = (float*)p; p += 8192 * 4;
    float* Wvt = (float*)p; p += 8192 * 4;
    float* Wet = (float*)p; p += 4096 * 4;
    unsigned short* wsW = (unsigned short*)p; p += W_TOT * 2;
    float* bqt = (float*)p; p += 128 * 4;
    float* bkt = (float*)p; p += 128 * 4;
    float* bvt = (float*)p; p += 128 * 4;

    k_pre<<<196, 256, 0, stream>>>(Wq, Wk, Wv, We, Wp, W1, W2, bq, bk, bv,
                                   Wqt, Wkt, Wvt, Wet, wsW, bqt, bkt, bvt,
                                   deg, n);
    k_bucket<<<(E + 255) / 256, 256, 0, stream>>>(ei, deg, bucket2, E, n);
    k_qkv<<<(n + 31) / 32, 256, 0, stream>>>(x, Wqt, Wkt, Wvt, bqt, bkt, bvt,
                                             g1, b1, We, qx, kbf, vbf, n);
    k_attn<<<(n + 3) / 4, 256, 0, stream>>>(qx, kbf, vbf, ea, deg, bucket2,
                                            Wet, aggbf, n, E);
    int nb16 = (n + 15) >> 4;
    int blocks = (nb16 + 3) / 4;
    if (blocks > 391) blocks = 391;   // 2 blocks/CU resident, waves grid-stride
    k_post<<<blocks, 256, 0, stream>>>((const unsigned short*)aggbf, wsW,
                                       bp, x, g2, b2, b1f, b2f,
                                       (float*)d_out, n);
}

// Round 6
// 325.789 us; speedup vs baseline: 1.5587x; 1.1183x over previous
//
#include <hip/hip_runtime.h>
#include <math.h>
#include <stdint.h>

// N=50000, E=600000, IN_CH=64, HEADS=2, C=64, HC=128, EDGE_DIM=32
// Layouts:
//   qx  (uint/float mix): [node][128 dwords] = 64 uints bf16-packed q (both heads
//        per channel) followed by 64 floats wq interleaved [d*2+h]. Read directly
//        (no LDS) by k_attn: lane l takes uint4 q[4l..4l+3] + float4 wq[4l..4l+3].
//   k/v (bf16 packed uint): [node][c] -> both heads at channel c in one uint
//   bucket_e (int) / bucket_s (ushort): [tgt][slot] -> edge id / src node
//   aggs (bf16 ushort): [node][192]: [0..127] = acc*r (cin=c*2+h),
//        [128..191] = S*r ([d*2+h]). k_post GEMM1 consumes K=192 directly;
//        the We^T S GEMV is folded into k_post via M = We @ Wp (precomputed).
//   wsW (bf16 ushort): [WpT|M][o][k]@stride200 | W1T[o][k]@88 | W2T[o][k]@88
// All data-derived indices are clamped: no input value can cause OOB.

typedef float f32x4 __attribute__((ext_vector_type(4)));
typedef __bf16 bf16x8 __attribute__((ext_vector_type(8)));
typedef unsigned int u32x4 __attribute__((ext_vector_type(4)));

#define WPM_S 200
#define W1_OFF 12800
#define W2_OFF 18432
#define W_TOT 24064
#define H_S 72

__device__ __forceinline__ unsigned pack_bf16(float2 v) {
    unsigned a = __builtin_bit_cast(unsigned, v.x);
    unsigned b = __builtin_bit_cast(unsigned, v.y);
    a = (a + 0x7FFFu + ((a >> 16) & 1u)) >> 16;   // RNE
    b = (b + 0x7FFFu + ((b >> 16) & 1u)) >> 16;
    return a | (b << 16);
}
__device__ __forceinline__ float2 unpack_bf16(unsigned p) {
    float x = __builtin_bit_cast(float, p << 16);
    float y = __builtin_bit_cast(float, p & 0xFFFF0000u);
    return make_float2(x, y);
}
__device__ __forceinline__ unsigned short bf16r(float x) {
    unsigned u = __builtin_bit_cast(unsigned, x);
    return (unsigned short)((u + 0x7FFFu + ((u >> 16) & 1u)) >> 16);
}

__device__ __forceinline__ f32x4 mfma16(bf16x8 a, bf16x8 b, f32x4 c) {
    return __builtin_amdgcn_mfma_f32_16x16x32_bf16(a, b, c, 0, 0, 0);
}
__device__ __forceinline__ bf16x8 frag_ld(const unsigned short* p) {
    return __builtin_bit_cast(bf16x8, *(const u32x4*)p);
}

// deg zero + weight re-layouts + M = We@Wp fold (per head), one launch.
__global__ void k_pre(const float* __restrict__ Wq, const float* __restrict__ Wk,
                      const float* __restrict__ Wv, const float* __restrict__ We,
                      const float* __restrict__ Wp, const float* __restrict__ W1,
                      const float* __restrict__ W2, const float* __restrict__ bq,
                      const float* __restrict__ bk, const float* __restrict__ bv,
                      float* __restrict__ Wqt, float* __restrict__ Wkt,
                      float* __restrict__ Wvt,
                      unsigned short* __restrict__ wsW, float* __restrict__ bqt,
                      float* __restrict__ bkt, float* __restrict__ bvt,
                      int* __restrict__ deg, int n) {
    int idx = blockIdx.x * 256 + threadIdx.x;
    for (int i = idx; i < n; i += gridDim.x * 256) deg[i] = 0;
    if (idx < 8192) {
        // Wq/Wk/Wv: [cin][h*64+c] -> [cin][c*2+h]
        int cin = idx >> 7, j = idx & 127, h = j >> 6, c = j & 63;
        int dst = cin * 128 + c * 2 + h;
        Wqt[dst] = Wq[idx];
        Wkt[dst] = Wk[idx];
        Wvt[dst] = Wv[idx];
        // WpT bf16 [o][k], k=cin=c*2+h -> orig row (k&1)*64 + (k>>1)
        int o = idx >> 7, k = idx & 127;
        wsW[o * WPM_S + k] = bf16r(Wp[((k & 1) * 64 + (k >> 1)) * 64 + o]);
    }
    if (idx < 4096) {
        // W1T/W2T bf16 [o][k]
        int o = idx >> 6, k = idx & 63;
        wsW[W1_OFF + o * 88 + k] = bf16r(W1[k * 64 + o]);
        wsW[W2_OFF + o * 88 + k] = bf16r(W2[k * 64 + o]);
        // M[dh][o2] = sum_c We[d][h*64+c] * Wp[h*64+c][o2], stored at k=128+dh
        int o2 = idx & 63, dh = idx >> 6, d = dh >> 1, h = dh & 1;
        float s = 0.f;
        for (int c = 0; c < 64; ++c)
            s += We[d * 128 + h * 64 + c] * Wp[(h * 64 + c) * 64 + o2];
        wsW[o2 * WPM_S + 128 + dh] = bf16r(s);
    }
    if (idx < 128) {
        int h = idx >> 6, c = idx & 63;
        bqt[c * 2 + h] = bq[idx];
        bkt[c * 2 + h] = bk[idx];
        bvt[c * 2 + h] = bv[idx];
    }
}

// Bucket build only: one thread per edge.
__global__ __launch_bounds__(256) void k_bucket(
    const int* __restrict__ ei, int* __restrict__ deg,
    int* __restrict__ bucket_e, unsigned short* __restrict__ bucket_s,
    int E, int n) {
    int e = blockIdx.x * 256 + threadIdx.x;
    if (e >= E) return;
    int src = ei[e], tgt = ei[E + e];
    src = min(max(src, 0), n - 1);
    tgt = min(max(tgt, 0), n - 1);
    int slot = atomicAdd(&deg[tgt], 1);
    if (slot < 64) {
        bucket_e[(size_t)tgt * 64 + slot] = e;
        bucket_s[(size_t)tgt * 64 + slot] = (unsigned short)src;
    }
}

// Fused LN1 + QKV + wq = We^T q. One wave per EIGHT nodes (weight reuse x8).
__global__ __launch_bounds__(256) void k_qkv(
    const float* __restrict__ x,
    const float* __restrict__ Wqt, const float* __restrict__ Wkt, const float* __restrict__ Wvt,
    const float* __restrict__ bqt, const float* __restrict__ bkt, const float* __restrict__ bvt,
    const float* __restrict__ g1, const float* __restrict__ b1,
    const float* __restrict__ We,   // original [d][h*64+c]
    unsigned* __restrict__ qx, unsigned* __restrict__ kbf,
    unsigned* __restrict__ vbf, int n) {
    __shared__ __align__(16) float hT[4][64][8];     // [wave][cin][node]  8 KB
    __shared__ __align__(16) float qs[4][2][8][64];  // [wave][h][node][c] 16 KB
    int wave = threadIdx.x >> 6, lane = threadIdx.x & 63;
    int node0 = blockIdx.x * 32 + wave * 8;
    if (node0 >= n) return;

    // ---- Phase 1: LayerNorm for 8 nodes (8 lanes per node) ----
    int b = lane >> 3, t = lane & 7;
    int nodeb = node0 + b;
    float4 xa = make_float4(0.f, 0.f, 0.f, 0.f), xb = xa;
    if (nodeb < n) {
        const float4* xp = (const float4*)(x + (size_t)nodeb * 64 + t * 8);
        xa = xp[0]; xb = xp[1];
    }
    float s1 = (xa.x + xa.y) + (xa.z + xa.w) + (xb.x + xb.y) + (xb.z + xb.w);
    float s2 = xa.x*xa.x + xa.y*xa.y + xa.z*xa.z + xa.w*xa.w
             + xb.x*xb.x + xb.y*xb.y + xb.z*xb.z + xb.w*xb.w;
#pragma unroll
    for (int m = 1; m < 8; m <<= 1) {
        s1 += __shfl_xor(s1, m);
        s2 += __shfl_xor(s2, m);
    }
    float mean = s1 * 0.015625f;
    float var  = s2 * 0.015625f - mean * mean;
    float rstd = rsqrtf(var + 1e-5f);
    float4 ga = ((const float4*)(g1 + t * 8))[0];
    float4 gb = ((const float4*)(g1 + t * 8))[1];
    float4 ba = ((const float4*)(b1 + t * 8))[0];
    float4 bb = ((const float4*)(b1 + t * 8))[1];
    float hv[8];
    hv[0] = (xa.x - mean) * rstd * ga.x + ba.x;
    hv[1] = (xa.y - mean) * rstd * ga.y + ba.y;
    hv[2] = (xa.z - mean) * rstd * ga.z + ba.z;
    hv[3] = (xa.w - mean) * rstd * ga.w + ba.w;
    hv[4] = (xb.x - mean) * rstd * gb.x + bb.x;
    hv[5] = (xb.y - mean) * rstd * gb.y + bb.y;
    hv[6] = (xb.z - mean) * rstd * gb.z + bb.z;
    hv[7] = (xb.w - mean) * rstd * gb.w + bb.w;
#pragma unroll
    for (int j = 0; j < 8; ++j) hT[wave][t * 8 + j][b] = hv[j];
    // per-wave LDS, wave-lockstep: no barrier needed

    // ---- Phase 2: QKV projection, 8 nodes per weight load ----
    const float2* Wq2 = (const float2*)Wqt;
    const float2* Wk2 = (const float2*)Wkt;
    const float2* Wv2 = (const float2*)Wvt;
    float2 bqv = ((const float2*)bqt)[lane];
    float2 bkv = ((const float2*)bkt)[lane];
    float2 bvv = ((const float2*)bvt)[lane];
    float2 qa[8], ka[8], va[8];
#pragma unroll
    for (int nb = 0; nb < 8; ++nb) { qa[nb] = bqv; ka[nb] = bkv; va[nb] = bvv; }

#pragma unroll 4
    for (int cin = 0; cin < 64; ++cin) {
        float2 w_q = Wq2[cin * 64 + lane];
        float2 w_k = Wk2[cin * 64 + lane];
        float2 w_v = Wv2[cin * 64 + lane];
        const float4* hp = (const float4*)&hT[wave][cin][0];
        float4 h0 = hp[0], h1 = hp[1];   // b128 broadcast
        float hs[8] = {h0.x, h0.y, h0.z, h0.w, h1.x, h1.y, h1.z, h1.w};
#pragma unroll
        for (int nb = 0; nb < 8; ++nb) {
            qa[nb].x += hs[nb] * w_q.x; qa[nb].y += hs[nb] * w_q.y;
            ka[nb].x += hs[nb] * w_k.x; ka[nb].y += hs[nb] * w_k.y;
            va[nb].x += hs[nb] * w_v.x; va[nb].y += hs[nb] * w_v.y;
        }
    }

    // ---- Phase 3: stores + stage q in LDS for phase 4 ----
#pragma unroll
    for (int nb = 0; nb < 8; ++nb) {
        int nd = node0 + nb;
        if (nd < n) {
            qx[(size_t)nd * 128 + lane] = pack_bf16(qa[nb]);
            kbf[(size_t)nd * 64 + lane] = pack_bf16(ka[nb]);
            vbf[(size_t)nd * 64 + lane] = pack_bf16(va[nb]);
        }
        qs[wave][0][nb][lane] = qa[nb].x;
        qs[wave][1][nb][lane] = qa[nb].y;
    }

    // ---- Phase 4: wq = We^T q -> qx[node][64 + d*2 + h], 8 nodes per We load ----
    int hh = lane >> 5, d = lane & 31;
    const float4* Wr = (const float4*)(We + d * 128 + hh * 64);
    float wqa[8] = {0.f, 0.f, 0.f, 0.f, 0.f, 0.f, 0.f, 0.f};
#pragma unroll 4
    for (int c4 = 0; c4 < 16; ++c4) {
        float4 w = Wr[c4];
#pragma unroll
        for (int nb = 0; nb < 8; ++nb) {
            float4 qv = *(const float4*)&qs[wave][hh][nb][c4 * 4];  // broadcast
            wqa[nb] += w.x * qv.x + w.y * qv.y + w.z * qv.z + w.w * qv.w;
        }
    }
#pragma unroll
    for (int nb = 0; nb < 8; ++nb)
        if (node0 + nb < n)
            ((float*)qx)[(size_t)(node0 + nb) * 128 + 64 + d * 2 + hh] = wqa[nb];
}

// Merged attention v3: edge-parallel (4 edges x 16 lanes) + SOFTWARE PIPELINE
// (next iteration's k/v/edge_attr gathers issued before current compute) +
// ZERO LDS (q/wq direct loads; acc relayout via cndmask; We^T S GEMV folded
// into k_post through M = We@Wp). Output row: [acc*r (128 bf16) | S*r (64 bf16)].
__global__ __launch_bounds__(256) void k_attn(
    const unsigned* __restrict__ qx, const unsigned* __restrict__ kbf,
    const unsigned* __restrict__ vbf, const float* __restrict__ edge_attr,
    const int* __restrict__ deg, const int* __restrict__ bucket_e,
    const unsigned short* __restrict__ bucket_s,
    unsigned* __restrict__ aggs, int n, int E) {
    int wave = threadIdx.x >> 6, lane = threadIdx.x & 63;
    int node = blockIdx.x * 4 + wave;
    if (node >= n) return;
    int sub = lane >> 4, l = lane & 15;

    // Per-lane q fragment (channels 4l..4l+3) and wq fragment (dims 2l,2l+1).
    uint4 qq = ((const uint4*)qx)[(size_t)node * 32 + l];
    float4 w4 = ((const float4*)qx)[(size_t)node * 32 + 16 + l];
    float2 q0 = unpack_bf16(qq.x), q1 = unpack_bf16(qq.y),
           q2 = unpack_bf16(qq.z), q3 = unpack_bf16(qq.w);

    int dcount = min(deg[node], 64);
    int eid_l = 0, src_l = 0;
    if (lane < dcount) {
        eid_l = min(max(bucket_e[(size_t)node * 64 + lane], 0), E - 1);
        src_l = min((int)bucket_s[(size_t)node * 64 + lane], n - 1);
    }

    const uint4* kb4 = (const uint4*)kbf;
    const uint4* vb4 = (const uint4*)vbf;
    const float2* ea2 = (const float2*)edge_attr;

    float accA[4] = {0.f, 0.f, 0.f, 0.f}, accB[4] = {0.f, 0.f, 0.f, 0.f};
    float aS0 = 0.f, aS1 = 0.f, bS0 = 0.f, bS1 = 0.f;
    float den0 = 0.f, den1 = 0.f;

    // Prefetch iteration 0.
    uint4 kk, vv; float2 a2;
    {
        int jj = sub & 63;
        int ej = __shfl(eid_l, jj), sj = __shfl(src_l, jj);
        kk = kb4[(size_t)sj * 16 + l];
        vv = vb4[(size_t)sj * 16 + l];
        a2 = ea2[(size_t)ej * 16 + l];
    }
    for (int i = 0; i < dcount; i += 4) {
        uint4 kc = kk, vc = vv; float2 ac = a2;
        bool valid = (i + sub) < dcount;
        int inx = i + 4;
        if (inx < dcount) {   // issue NEXT gathers before current compute
            int jj = (inx + sub) & 63;
            int ej = __shfl(eid_l, jj), sj = __shfl(src_l, jj);
            kk = kb4[(size_t)sj * 16 + l];
            vv = vb4[(size_t)sj * 16 + l];
            a2 = ea2[(size_t)ej * 16 + l];
        }
        float2 k0 = unpack_bf16(kc.x), k1 = unpack_bf16(kc.y),
               k2 = unpack_bf16(kc.z), k3 = unpack_bf16(kc.w);
        float r0 = q0.x * k0.x + q1.x * k1.x + q2.x * k2.x + q3.x * k3.x
                 + w4.x * ac.x + w4.z * ac.y;
        float r1 = q0.y * k0.y + q1.y * k1.y + q2.y * k2.y + q3.y * k3.y
                 + w4.y * ac.x + w4.w * ac.y;
#pragma unroll
        for (int m = 1; m < 16; m <<= 1) {    // 4 steps, stays in 16-lane group
            r0 += __shfl_xor(r0, m);
            r1 += __shfl_xor(r1, m);
        }
        float ex0 = valid ? __expf(r0 * 0.125f) : 0.f;
        float ex1 = valid ? __expf(r1 * 0.125f) : 0.f;
        float2 v0 = unpack_bf16(vc.x), v1 = unpack_bf16(vc.y),
               v2 = unpack_bf16(vc.z), v3 = unpack_bf16(vc.w);
        accA[0] += ex0 * v0.x; accB[0] += ex1 * v0.y;
        accA[1] += ex0 * v1.x; accB[1] += ex1 * v1.y;
        accA[2] += ex0 * v2.x; accB[2] += ex1 * v2.y;
        accA[3] += ex0 * v3.x; accB[3] += ex1 * v3.y;
        aS0 += ex0 * ac.x; aS1 += ex1 * ac.x;
        bS0 += ex0 * ac.y; bS1 += ex1 * ac.y;
        den0 += ex0; den1 += ex1;
    }

    // Single cross-group reduce per node (masks 16, 32).
#pragma unroll
    for (int m = 16; m < 64; m <<= 1) {
#pragma unroll
        for (int j = 0; j < 4; ++j) {
            accA[j] += __shfl_xor(accA[j], m);
            accB[j] += __shfl_xor(accB[j], m);
        }
        aS0 += __shfl_xor(aS0, m); aS1 += __shfl_xor(aS1, m);
        bS0 += __shfl_xor(bS0, m); bS1 += __shfl_xor(bS1, m);
        den0 += __shfl_xor(den0, m); den1 += __shfl_xor(den1, m);
    }

    float r0 = 1.0f / (den0 + 1e-8f);
    float r1 = 1.0f / (den1 + 1e-8f);

    // acc store: lane (sub,l) takes channel c = 4l+sub (static selects, no LDS).
    float va = sub == 0 ? accA[0] : sub == 1 ? accA[1] : sub == 2 ? accA[2] : accA[3];
    float vb = sub == 0 ? accB[0] : sub == 1 ? accB[1] : sub == 2 ? accB[2] : accB[3];
    aggs[(size_t)node * 96 + 4 * l + sub] =
        pack_bf16(make_float2(va * r0, vb * r1));

    // S store (normalized): k = 128 + d*2+h; lane group sub==0 writes 8 B.
    if (sub == 0) {
        unsigned s0 = pack_bf16(make_float2(aS0 * r0, aS1 * r1));   // d=2l
        unsigned s1 = pack_bf16(make_float2(bS0 * r0, bS1 * r1));   // d=2l+1
        *(uint2*)&aggs[(size_t)node * 96 + 64 + 2 * l] = make_uint2(s0, s1);
    }
}

// Epilogue v5: MFMA, GEMM1 K=192 (acc | S folded via M). One wave per 16 nodes.
__global__ __launch_bounds__(256) void k_post(
    const unsigned short* __restrict__ aggsb,  // [node][192] bf16
    const unsigned short* __restrict__ wsW,    // packed [WpT|M]|W1T|W2T bf16
    const float* __restrict__ bp, const float* __restrict__ x,
    const float* __restrict__ g2, const float* __restrict__ b2,
    const float* __restrict__ b1f, const float* __restrict__ b2f,
    float* __restrict__ out, int n) {
    __shared__ __align__(16) unsigned short sW[W_TOT];           // 48128 B
    __shared__ __align__(16) unsigned short hb[4][2][16 * H_S];  // 18432 B
    int tid = threadIdx.x;
    for (int i = tid; i < W_TOT / 8; i += 256)
        ((u32x4*)sW)[i] = ((const u32x4*)wsW)[i];
    __syncthreads();

    int wave = tid >> 6, lane = tid & 63;
    int cl = lane & 15, kg = lane >> 4;   // col-lane, k-group
    unsigned short* h2 = hb[wave][0];
    unsigned short* h3 = hb[wave][1];

    // hoisted per-column constants: c = t*16 + cl
    float bp_c[4], g2_c[4], b2_c[4], b1_c[4], bf2_c[4];
#pragma unroll
    for (int t = 0; t < 4; ++t) {
        int c = t * 16 + cl;
        bp_c[t] = bp[c];
        g2_c[t] = g2[c];
        b2_c[t] = b2[c];
        b1_c[t] = b1f[c];
        bf2_c[t] = b2f[c];
    }

    int wid = blockIdx.x * 4 + wave;
    int nbatch = (n + 15) >> 4;
    int nwaves = gridDim.x * 4;
    for (int bt = wid; bt < nbatch; bt += nwaves) {
        int node0 = bt * 16;

        // ---- GEMM1: acc1 = [agg|S](16x192,bf16) @ [WpT|M] + bp + x ----
        f32x4 acc1[4];
#pragma unroll
        for (int t = 0; t < 4; ++t) acc1[t] = (f32x4){0.f, 0.f, 0.f, 0.f};
        int arow = min(node0 + cl, n - 1);
#pragma unroll
        for (int s = 0; s < 6; ++s) {
            bf16x8 af = frag_ld(aggsb + (size_t)arow * 192 + s * 32 + kg * 8);
#pragma unroll
            for (int t = 0; t < 4; ++t) {
                bf16x8 bf = frag_ld(sW + (t * 16 + cl) * WPM_S + s * 32 + kg * 8);
                acc1[t] = mfma16(af, bf, acc1[t]);
            }
        }
#pragma unroll
        for (int t = 0; t < 4; ++t) {
#pragma unroll
            for (int j = 0; j < 4; ++j) {
                int nd = min(node0 + kg * 4 + j, n - 1);
                acc1[t][j] += bp_c[t] + x[(size_t)nd * 64 + t * 16 + cl];
            }
        }

        // ---- LN2 over 64 channels of rows r = kg*4+j ----
        float mean[4], rstd[4];
#pragma unroll
        for (int j = 0; j < 4; ++j) {
            float s1 = acc1[0][j] + acc1[1][j] + acc1[2][j] + acc1[3][j];
            float s2 = acc1[0][j] * acc1[0][j] + acc1[1][j] * acc1[1][j]
                     + acc1[2][j] * acc1[2][j] + acc1[3][j] * acc1[3][j];
#pragma unroll
            for (int m = 1; m < 16; m <<= 1) {
                s1 += __shfl_xor(s1, m);
                s2 += __shfl_xor(s2, m);
            }
            mean[j] = s1 * 0.015625f;
            float var = s2 * 0.015625f - mean[j] * mean[j];
            rstd[j] = rsqrtf(var + 1e-5f);
        }
#pragma unroll
        for (int t = 0; t < 4; ++t)
#pragma unroll
            for (int j = 0; j < 4; ++j) {
                float v = (acc1[t][j] - mean[j]) * rstd[j] * g2_c[t] + b2_c[t];
                h2[(kg * 4 + j) * H_S + t * 16 + cl] = bf16r(v);
            }
        asm volatile("s_waitcnt lgkmcnt(0)" ::: "memory");

        // ---- GEMM2: f = h2(16x64) @ W1 + b1; gelu -> h3 ----
        f32x4 acc2[4];
#pragma unroll
        for (int t = 0; t < 4; ++t)
            acc2[t] = (f32x4){b1_c[t], b1_c[t], b1_c[t], b1_c[t]};
#pragma unroll
        for (int s = 0; s < 2; ++s) {
            bf16x8 af = frag_ld(h2 + cl * H_S + s * 32 + kg * 8);
#pragma unroll
            for (int t = 0; t < 4; ++t) {
                bf16x8 bf = frag_ld(sW + W1_OFF + (t * 16 + cl) * 88 + s * 32 + kg * 8);
                acc2[t] = mfma16(af, bf, acc2[t]);
            }
        }
#pragma unroll
        for (int t = 0; t < 4; ++t)
#pragma unroll
            for (int j = 0; j < 4; ++j) {
                float v = acc2[t][j];
                v = 0.5f * v * (1.0f + erff(v * 0.70710678118654752f));
                h3[(kg * 4 + j) * H_S + t * 16 + cl] = bf16r(v);
            }
        asm volatile("s_waitcnt lgkmcnt(0)" ::: "memory");

        // ---- GEMM3: y = gelu @ W2 + b2f + acc1 (residual 2) ----
        f32x4 acc3[4];
#pragma unroll
        for (int t = 0; t < 4; ++t) {
            acc3[t] = acc1[t];
#pragma unroll
            for (int j = 0; j < 4; ++j) acc3[t][j] += bf2_c[t];
        }
#pragma unroll
        for (int s = 0; s < 2; ++s) {
            bf16x8 af = frag_ld(h3 + cl * H_S + s * 32 + kg * 8);
#pragma unroll
            for (int t = 0; t < 4; ++t) {
                bf16x8 bf = frag_ld(sW + W2_OFF + (t * 16 + cl) * 88 + s * 32 + kg * 8);
                acc3[t] = mfma16(af, bf, acc3[t]);
            }
        }
#pragma unroll
        for (int t = 0; t < 4; ++t)
#pragma unroll
            for (int j = 0; j < 4; ++j) {
                int r = node0 + kg * 4 + j;
                if (r < n) out[(size_t)r * 64 + t * 16 + cl] = acc3[t][j];
            }
    }
}

extern "C" void kernel_launch(void* const* d_in, const int* in_sizes, int n_in,
                              void* d_out, int out_size, void* d_ws, size_t ws_size,
                              hipStream_t stream) {
    const float* x  = (const float*)d_in[0];
    const int*   ei = (const int*)d_in[1];
    const float* ea = (const float*)d_in[2];
    const float* Wq = (const float*)d_in[3];
    const float* bq = (const float*)d_in[4];
    const float* Wk = (const float*)d_in[5];
    const float* bk = (const float*)d_in[6];
    const float* Wv = (const float*)d_in[7];
    const float* bv = (const float*)d_in[8];
    const float* We = (const float*)d_in[9];
    const float* Wp = (const float*)d_in[10];
    const float* bp = (const float*)d_in[11];
    const float* g1 = (const float*)d_in[12];
    const float* b1 = (const float*)d_in[13];
    const float* g2 = (const float*)d_in[14];
    const float* b2 = (const float*)d_in[15];
    const float* W1 = (const float*)d_in[16];
    const float* b1f = (const float*)d_in[17];
    const float* W2 = (const float*)d_in[18];
    const float* b2f = (const float*)d_in[19];

    const int n = in_sizes[0] / 64;   // 50000
    const int E = in_sizes[2] / 32;   // 600000

    // Workspace carve (~90 MB).
    char* p = (char*)d_ws;
    unsigned* qx = (unsigned*)p; p += (size_t)n * 128 * 4;   // q bf16 + wq fused
    unsigned* kbf = (unsigned*)p; p += (size_t)n * 64 * 4;
    unsigned* vbf = (unsigned*)p; p += (size_t)n * 64 * 4;
    int* deg   = (int*)p;   p += (size_t)n * 4;
    p = (char*)(((uintptr_t)p + 15) & ~(uintptr_t)15);
    int* bucket_e = (int*)p; p += (size_t)n * 64 * 4;
    unsigned short* bucket_s = (unsigned short*)p; p += (size_t)n * 64 * 2;
    p = (char*)(((uintptr_t)p + 15) & ~(uintptr_t)15);
    unsigned* aggs = (unsigned*)p; p += (size_t)n * 96 * 4;   // 192 bf16/node
    float* Wqt = (float*)p; p += 8192 * 4;
    float* Wkt = (float*)p; p += 8192 * 4;
    float* Wvt = (float*)p; p += 8192 * 4;
    unsigned short* wsW = (unsigned short*)p; p += W_TOT * 2;
    float* bqt = (float*)p; p += 128 * 4;
    float* bkt = (float*)p; p += 128 * 4;
    float* bvt = (float*)p; p += 128 * 4;

    k_pre<<<196, 256, 0, stream>>>(Wq, Wk, Wv, We, Wp, W1, W2, bq, bk, bv,
                                   Wqt, Wkt, Wvt, wsW, bqt, bkt, bvt,
                                   deg, n);
    k_bucket<<<(E + 255) / 256, 256, 0, stream>>>(ei, deg, bucket_e, bucket_s,
                                                  E, n);
    k_qkv<<<(n + 31) / 32, 256, 0, stream>>>(x, Wqt, Wkt, Wvt, bqt, bkt, bvt,
                                             g1, b1, We, qx, kbf, vbf, n);
    k_attn<<<(n + 3) / 4, 256, 0, stream>>>(qx, kbf, vbf, ea, deg,
                                            bucket_e, bucket_s, aggs, n, E);
    int nb16 = (n + 15) >> 4;
    int blocks = (nb16 + 3) / 4;
    if (blocks > 391) blocks = 391;   // 2 blocks/CU resident, waves grid-stride
    k_post<<<blocks, 256, 0, stream>>>((const unsigned short*)aggs, wsW,
                                       bp, x, g2, b2, b1f, b2f,
                                       (float*)d_out, n);
}

// Round 7
// 293.447 us; speedup vs baseline: 1.7305x; 1.1102x over previous
//
#include <hip/hip_runtime.h>
#include <math.h>
#include <stdint.h>

// N=50000, E=600000, IN_CH=64, HEADS=2, C=64, HC=128, EDGE_DIM=32
// Layouts:
//   qx  (uint/float mix): [node][128 dwords] = 64 uints bf16-packed q (both heads
//        per channel) followed by 64 floats wq interleaved [d*2+h]. Read directly
//        (no LDS) by k_attn: lane l takes uint4 q[4l..4l+3] + float4 wq[4l..4l+3].
//   k/v (bf16 packed uint): [node][c] -> both heads at channel c in one uint
//   bucket_e (int) / bucket_s (ushort): [tgt][slot] -> edge id / src node
//   aggs (bf16 ushort): [node][192]: [0..127] = acc*r (cin=c*2+h),
//        [128..191] = S*r ([d*2+h]). k_post GEMM1 consumes K=192 directly.
//   wsW (bf16 ushort): [WpT|M][o][k]@stride200 | W1T[o][k]@88 | W2T[o][k]@88
//   wcat (bf16 ushort): [448][72] o-major k-contiguous: rows 0..127 = Wq^T
//        (o=h*64+c), 128..255 = Wk^T, 256..383 = Wv^T, 384..447 = wq-fold
//        M2[o''=d*2+h][cin] = sum_c Wq[cin][h*64+c]*We[d][h*64+c].
//   bcat (float): [448] biases matching wcat rows (wq rows get bias-fold).
// All data-derived indices are clamped: no input value can cause OOB.

typedef float f32x4 __attribute__((ext_vector_type(4)));
typedef __bf16 bf16x8 __attribute__((ext_vector_type(8)));
typedef unsigned int u32x4 __attribute__((ext_vector_type(4)));

#define WPM_S 200
#define W1_OFF 12800
#define W2_OFF 18432
#define W_TOT 24064
#define H_S 72
#define WC_S 72
#define WC_TOT (448 * 72)

__device__ __forceinline__ unsigned pack_bf16(float2 v) {
    unsigned a = __builtin_bit_cast(unsigned, v.x);
    unsigned b = __builtin_bit_cast(unsigned, v.y);
    a = (a + 0x7FFFu + ((a >> 16) & 1u)) >> 16;   // RNE
    b = (b + 0x7FFFu + ((b >> 16) & 1u)) >> 16;
    return a | (b << 16);
}
__device__ __forceinline__ float2 unpack_bf16(unsigned p) {
    float x = __builtin_bit_cast(float, p << 16);
    float y = __builtin_bit_cast(float, p & 0xFFFF0000u);
    return make_float2(x, y);
}
__device__ __forceinline__ unsigned short bf16r(float x) {
    unsigned u = __builtin_bit_cast(unsigned, x);
    return (unsigned short)((u + 0x7FFFu + ((u >> 16) & 1u)) >> 16);
}

__device__ __forceinline__ f32x4 mfma16(bf16x8 a, bf16x8 b, f32x4 c) {
    return __builtin_amdgcn_mfma_f32_16x16x32_bf16(a, b, c, 0, 0, 0);
}
__device__ __forceinline__ bf16x8 frag_ld(const unsigned short* p) {
    return __builtin_bit_cast(bf16x8, *(const u32x4*)p);
}

// deg zero + all weight re-layouts/folds, one launch.
__global__ void k_pre(const float* __restrict__ Wq, const float* __restrict__ Wk,
                      const float* __restrict__ Wv, const float* __restrict__ We,
                      const float* __restrict__ Wp, const float* __restrict__ W1,
                      const float* __restrict__ W2, const float* __restrict__ bq,
                      const float* __restrict__ bk, const float* __restrict__ bv,
                      unsigned short* __restrict__ wsW,
                      unsigned short* __restrict__ wcat, float* __restrict__ bcat,
                      int* __restrict__ deg, int n) {
    int idx = blockIdx.x * 256 + threadIdx.x;
    for (int i = idx; i < n; i += gridDim.x * 256) deg[i] = 0;
    if (idx < 8192) {
        // WpT bf16 [o][k], k=cin=c*2+h -> orig row (k&1)*64 + (k>>1)
        int o = idx >> 7, k = idx & 127;
        wsW[o * WPM_S + k] = bf16r(Wp[((k & 1) * 64 + (k >> 1)) * 64 + o]);
        // wcat q/k/v rows: row j (=h*64+c), col cin
        int cin = idx >> 7, j = idx & 127;
        wcat[j * WC_S + cin] = bf16r(Wq[cin * 128 + j]);
        wcat[(128 + j) * WC_S + cin] = bf16r(Wk[cin * 128 + j]);
        wcat[(256 + j) * WC_S + cin] = bf16r(Wv[cin * 128 + j]);
    }
    if (idx < 4096) {
        // W1T/W2T bf16 [o][k]
        int o = idx >> 6, k = idx & 63;
        wsW[W1_OFF + o * 88 + k] = bf16r(W1[k * 64 + o]);
        wsW[W2_OFF + o * 88 + k] = bf16r(W2[k * 64 + o]);
        // M[dh][o2] for k_post S-fold (stored at k=128+dh of WpT rows)
        int o2 = idx & 63, dh = idx >> 6, d = dh >> 1, h = dh & 1;
        float s = 0.f;
        for (int c = 0; c < 64; ++c)
            s += We[d * 128 + h * 64 + c] * Wp[(h * 64 + c) * 64 + o2];
        wsW[o2 * WPM_S + 128 + dh] = bf16r(s);
        // wcat wq-fold rows: M2[dh2][cin2] = sum_c Wq[cin2][h*64+c]*We[d][h*64+c]
        int cin2 = idx & 63, dh2 = idx >> 6, d2 = dh2 >> 1, h2 = dh2 & 1;
        float s2 = 0.f;
        for (int c = 0; c < 64; ++c)
            s2 += Wq[cin2 * 128 + h2 * 64 + c] * We[d2 * 128 + h2 * 64 + c];
        wcat[(384 + dh2) * WC_S + cin2] = bf16r(s2);
    }
    if (idx < 384)
        bcat[idx] = idx < 128 ? bq[idx] : idx < 256 ? bk[idx - 128] : bv[idx - 256];
    if (idx < 64) {
        int d = idx >> 1, h = idx & 1;
        float s = 0.f;
        for (int c = 0; c < 64; ++c)
            s += bq[h * 64 + c] * We[d * 128 + h * 64 + c];
        bcat[384 + idx] = s;
    }
}

// Bucket build only: one thread per edge.
__global__ __launch_bounds__(256) void k_bucket(
    const int* __restrict__ ei, int* __restrict__ deg,
    int* __restrict__ bucket_e, unsigned short* __restrict__ bucket_s,
    int E, int n) {
    int e = blockIdx.x * 256 + threadIdx.x;
    if (e >= E) return;
    int src = ei[e], tgt = ei[E + e];
    src = min(max(src, 0), n - 1);
    tgt = min(max(tgt, 0), n - 1);
    int slot = atomicAdd(&deg[tgt], 1);
    if (slot < 64) {
        bucket_e[(size_t)tgt * 64 + slot] = e;
        bucket_s[(size_t)tgt * 64 + slot] = (unsigned short)src;
    }
}

// QKV v3: MFMA. One wave per 16 nodes. LN1 computed directly in A-fragment
// layout (lane (cl,kg) owns row node0+cl, channels {kg*8..+8, 32+kg*8..+8};
// row stats via shfl_xor masks 16,32 -- no LDS, no barrier). One GEMM
// [16x64]@[64x448] against concatenated wcat (q|k|v|wq-fold) staged in LDS.
// wq = We^T(q) folded into the SAME GEMM via M2 = Wq*We fold (k_pre).
// Output order h*64+c puts both heads of channel c in one lane (acc[t],
// acc[t+4]) -> local bf16 pack, no cross-lane traffic. 4 passes of 7 accs
// keep VGPR low. C-frag: col=lane&15, row=(lane>>4)*4+j [k_post-proven].
__global__ __launch_bounds__(256) void k_qkv(
    const float* __restrict__ x, const unsigned short* __restrict__ wcat,
    const float* __restrict__ bcat,
    const float* __restrict__ g1, const float* __restrict__ b1,
    unsigned* __restrict__ qx, unsigned* __restrict__ kbf,
    unsigned* __restrict__ vbf, int n) {
    __shared__ __align__(16) unsigned short sW[WC_TOT];   // 64512 B
    int tid = threadIdx.x;
    for (int i = tid; i < WC_TOT / 8; i += 256)
        ((u32x4*)sW)[i] = ((const u32x4*)wcat)[i];
    __syncthreads();

    int wave = tid >> 6, lane = tid & 63;
    int cl = lane & 15, kg = lane >> 4;
    int node0 = blockIdx.x * 64 + wave * 16;
    if (node0 >= n) return;
    int arow = min(node0 + cl, n - 1);

    // ---- LN1 in A-frag layout ----
    const float4* xp = (const float4*)(x + (size_t)arow * 64);
    float4 xv[4] = {xp[kg * 2], xp[kg * 2 + 1], xp[8 + kg * 2], xp[9 + kg * 2]};
    float s1 = 0.f, s2 = 0.f;
#pragma unroll
    for (int i = 0; i < 4; ++i) {
        s1 += (xv[i].x + xv[i].y) + (xv[i].z + xv[i].w);
        s2 += xv[i].x * xv[i].x + xv[i].y * xv[i].y
            + xv[i].z * xv[i].z + xv[i].w * xv[i].w;
    }
    s1 += __shfl_xor(s1, 16); s2 += __shfl_xor(s2, 16);
    s1 += __shfl_xor(s1, 32); s2 += __shfl_xor(s2, 32);
    float mean = s1 * 0.015625f;
    float var  = s2 * 0.015625f - mean * mean;
    float rstd = rsqrtf(var + 1e-5f);
    const float4* gp = (const float4*)g1;
    const float4* bp1 = (const float4*)b1;
    float4 gv[4] = {gp[kg * 2], gp[kg * 2 + 1], gp[8 + kg * 2], gp[9 + kg * 2]};
    float4 bv4[4] = {bp1[kg * 2], bp1[kg * 2 + 1], bp1[8 + kg * 2], bp1[9 + kg * 2]};
    unsigned fr[8];
#pragma unroll
    for (int i = 0; i < 4; ++i) {
        float h0 = (xv[i].x - mean) * rstd * gv[i].x + bv4[i].x;
        float h1 = (xv[i].y - mean) * rstd * gv[i].y + bv4[i].y;
        float h2 = (xv[i].z - mean) * rstd * gv[i].z + bv4[i].z;
        float h3 = (xv[i].w - mean) * rstd * gv[i].w + bv4[i].w;
        fr[i * 2]     = pack_bf16(make_float2(h0, h1));
        fr[i * 2 + 1] = pack_bf16(make_float2(h2, h3));
    }
    bf16x8 A0 = __builtin_bit_cast(bf16x8, (u32x4){fr[0], fr[1], fr[2], fr[3]});
    bf16x8 A1 = __builtin_bit_cast(bf16x8, (u32x4){fr[4], fr[5], fr[6], fr[7]});

    // ---- 4 passes x {q_h0,q_h1,k_h0,k_h1,v_h0,v_h1,wq} ----
#pragma unroll
    for (int tq = 0; tq < 4; ++tq) {
        int c = tq * 16 + cl;
        f32x4 aq0 = {bcat[c], bcat[c], bcat[c], bcat[c]};
        float b_;
        b_ = bcat[64 + c];  f32x4 aq1 = {b_, b_, b_, b_};
        b_ = bcat[128 + c]; f32x4 ak0 = {b_, b_, b_, b_};
        b_ = bcat[192 + c]; f32x4 ak1 = {b_, b_, b_, b_};
        b_ = bcat[256 + c]; f32x4 av0 = {b_, b_, b_, b_};
        b_ = bcat[320 + c]; f32x4 av1 = {b_, b_, b_, b_};
        b_ = bcat[384 + c]; f32x4 aw  = {b_, b_, b_, b_};
#pragma unroll
        for (int s = 0; s < 2; ++s) {
            bf16x8 A = s ? A1 : A0;
            int ko = s * 32 + kg * 8;
            aq0 = mfma16(A, frag_ld(sW + (size_t)(c) * WC_S + ko), aq0);
            aq1 = mfma16(A, frag_ld(sW + (size_t)(64 + c) * WC_S + ko), aq1);
            ak0 = mfma16(A, frag_ld(sW + (size_t)(128 + c) * WC_S + ko), ak0);
            ak1 = mfma16(A, frag_ld(sW + (size_t)(192 + c) * WC_S + ko), ak1);
            av0 = mfma16(A, frag_ld(sW + (size_t)(256 + c) * WC_S + ko), av0);
            av1 = mfma16(A, frag_ld(sW + (size_t)(320 + c) * WC_S + ko), av1);
            aw  = mfma16(A, frag_ld(sW + (size_t)(384 + c) * WC_S + ko), aw);
        }
#pragma unroll
        for (int j = 0; j < 4; ++j) {
            int node = node0 + kg * 4 + j;
            if (node < n) {
                qx[(size_t)node * 128 + c] = pack_bf16(make_float2(aq0[j], aq1[j]));
                kbf[(size_t)node * 64 + c] = pack_bf16(make_float2(ak0[j], ak1[j]));
                vbf[(size_t)node * 64 + c] = pack_bf16(make_float2(av0[j], av1[j]));
                ((float*)qx)[(size_t)node * 128 + 64 + c] = aw[j];
            }
        }
    }
}

// Merged attention v3: edge-parallel (4 edges x 16 lanes) + software pipeline
// + zero LDS; We^T S GEMV folded into k_post. Row: [acc*r 128 | S*r 64] bf16.
__global__ __launch_bounds__(256) void k_attn(
    const unsigned* __restrict__ qx, const unsigned* __restrict__ kbf,
    const unsigned* __restrict__ vbf, const float* __restrict__ edge_attr,
    const int* __restrict__ deg, const int* __restrict__ bucket_e,
    const unsigned short* __restrict__ bucket_s,
    unsigned* __restrict__ aggs, int n, int E) {
    int wave = threadIdx.x >> 6, lane = threadIdx.x & 63;
    int node = blockIdx.x * 4 + wave;
    if (node >= n) return;
    int sub = lane >> 4, l = lane & 15;

    uint4 qq = ((const uint4*)qx)[(size_t)node * 32 + l];
    float4 w4 = ((const float4*)qx)[(size_t)node * 32 + 16 + l];
    float2 q0 = unpack_bf16(qq.x), q1 = unpack_bf16(qq.y),
           q2 = unpack_bf16(qq.z), q3 = unpack_bf16(qq.w);

    int dcount = min(deg[node], 64);
    int eid_l = 0, src_l = 0;
    if (lane < dcount) {
        eid_l = min(max(bucket_e[(size_t)node * 64 + lane], 0), E - 1);
        src_l = min((int)bucket_s[(size_t)node * 64 + lane], n - 1);
    }

    const uint4* kb4 = (const uint4*)kbf;
    const uint4* vb4 = (const uint4*)vbf;
    const float2* ea2 = (const float2*)edge_attr;

    float accA[4] = {0.f, 0.f, 0.f, 0.f}, accB[4] = {0.f, 0.f, 0.f, 0.f};
    float aS0 = 0.f, aS1 = 0.f, bS0 = 0.f, bS1 = 0.f;
    float den0 = 0.f, den1 = 0.f;

    uint4 kk, vv; float2 a2;
    {
        int jj = sub & 63;
        int ej = __shfl(eid_l, jj), sj = __shfl(src_l, jj);
        kk = kb4[(size_t)sj * 16 + l];
        vv = vb4[(size_t)sj * 16 + l];
        a2 = ea2[(size_t)ej * 16 + l];
    }
    for (int i = 0; i < dcount; i += 4) {
        uint4 kc = kk, vc = vv; float2 ac = a2;
        bool valid = (i + sub) < dcount;
        int inx = i + 4;
        if (inx < dcount) {   // issue NEXT gathers before current compute
            int jj = (inx + sub) & 63;
            int ej = __shfl(eid_l, jj), sj = __shfl(src_l, jj);
            kk = kb4[(size_t)sj * 16 + l];
            vv = vb4[(size_t)sj * 16 + l];
            a2 = ea2[(size_t)ej * 16 + l];
        }
        float2 k0 = unpack_bf16(kc.x), k1 = unpack_bf16(kc.y),
               k2 = unpack_bf16(kc.z), k3 = unpack_bf16(kc.w);
        float r0 = q0.x * k0.x + q1.x * k1.x + q2.x * k2.x + q3.x * k3.x
                 + w4.x * ac.x + w4.z * ac.y;
        float r1 = q0.y * k0.y + q1.y * k1.y + q2.y * k2.y + q3.y * k3.y
                 + w4.y * ac.x + w4.w * ac.y;
#pragma unroll
        for (int m = 1; m < 16; m <<= 1) {
            r0 += __shfl_xor(r0, m);
            r1 += __shfl_xor(r1, m);
        }
        float ex0 = valid ? __expf(r0 * 0.125f) : 0.f;
        float ex1 = valid ? __expf(r1 * 0.125f) : 0.f;
        float2 v0 = unpack_bf16(vc.x), v1 = unpack_bf16(vc.y),
               v2 = unpack_bf16(vc.z), v3 = unpack_bf16(vc.w);
        accA[0] += ex0 * v0.x; accB[0] += ex1 * v0.y;
        accA[1] += ex0 * v1.x; accB[1] += ex1 * v1.y;
        accA[2] += ex0 * v2.x; accB[2] += ex1 * v2.y;
        accA[3] += ex0 * v3.x; accB[3] += ex1 * v3.y;
        aS0 += ex0 * ac.x; aS1 += ex1 * ac.x;
        bS0 += ex0 * ac.y; bS1 += ex1 * ac.y;
        den0 += ex0; den1 += ex1;
    }

#pragma unroll
    for (int m = 16; m < 64; m <<= 1) {
#pragma unroll
        for (int j = 0; j < 4; ++j) {
            accA[j] += __shfl_xor(accA[j], m);
            accB[j] += __shfl_xor(accB[j], m);
        }
        aS0 += __shfl_xor(aS0, m); aS1 += __shfl_xor(aS1, m);
        bS0 += __shfl_xor(bS0, m); bS1 += __shfl_xor(bS1, m);
        den0 += __shfl_xor(den0, m); den1 += __shfl_xor(den1, m);
    }

    float r0 = 1.0f / (den0 + 1e-8f);
    float r1 = 1.0f / (den1 + 1e-8f);

    float va = sub == 0 ? accA[0] : sub == 1 ? accA[1] : sub == 2 ? accA[2] : accA[3];
    float vb = sub == 0 ? accB[0] : sub == 1 ? accB[1] : sub == 2 ? accB[2] : accB[3];
    aggs[(size_t)node * 96 + 4 * l + sub] =
        pack_bf16(make_float2(va * r0, vb * r1));

    if (sub == 0) {
        unsigned s0 = pack_bf16(make_float2(aS0 * r0, aS1 * r1));   // d=2l
        unsigned s1 = pack_bf16(make_float2(bS0 * r0, bS1 * r1));   // d=2l+1
        *(uint2*)&aggs[(size_t)node * 96 + 64 + 2 * l] = make_uint2(s0, s1);
    }
}

// Epilogue v5: MFMA, GEMM1 K=192 (acc | S folded via M). One wave per 16 nodes.
__global__ __launch_bounds__(256) void k_post(
    const unsigned short* __restrict__ aggsb,  // [node][192] bf16
    const unsigned short* __restrict__ wsW,    // packed [WpT|M]|W1T|W2T bf16
    const float* __restrict__ bp, const float* __restrict__ x,
    const float* __restrict__ g2, const float* __restrict__ b2,
    const float* __restrict__ b1f, const float* __restrict__ b2f,
    float* __restrict__ out, int n) {
    __shared__ __align__(16) unsigned short sW[W_TOT];           // 48128 B
    __shared__ __align__(16) unsigned short hb[4][2][16 * H_S];  // 18432 B
    int tid = threadIdx.x;
    for (int i = tid; i < W_TOT / 8; i += 256)
        ((u32x4*)sW)[i] = ((const u32x4*)wsW)[i];
    __syncthreads();

    int wave = tid >> 6, lane = tid & 63;
    int cl = lane & 15, kg = lane >> 4;   // col-lane, k-group
    unsigned short* h2 = hb[wave][0];
    unsigned short* h3 = hb[wave][1];

    float bp_c[4], g2_c[4], b2_c[4], b1_c[4], bf2_c[4];
#pragma unroll
    for (int t = 0; t < 4; ++t) {
        int c = t * 16 + cl;
        bp_c[t] = bp[c];
        g2_c[t] = g2[c];
        b2_c[t] = b2[c];
        b1_c[t] = b1f[c];
        bf2_c[t] = b2f[c];
    }

    int wid = blockIdx.x * 4 + wave;
    int nbatch = (n + 15) >> 4;
    int nwaves = gridDim.x * 4;
    for (int bt = wid; bt < nbatch; bt += nwaves) {
        int node0 = bt * 16;

        // ---- GEMM1: acc1 = [agg|S](16x192,bf16) @ [WpT|M] + bp + x ----
        f32x4 acc1[4];
#pragma unroll
        for (int t = 0; t < 4; ++t) acc1[t] = (f32x4){0.f, 0.f, 0.f, 0.f};
        int arow = min(node0 + cl, n - 1);
#pragma unroll
        for (int s = 0; s < 6; ++s) {
            bf16x8 af = frag_ld(aggsb + (size_t)arow * 192 + s * 32 + kg * 8);
#pragma unroll
            for (int t = 0; t < 4; ++t) {
                bf16x8 bf = frag_ld(sW + (t * 16 + cl) * WPM_S + s * 32 + kg * 8);
                acc1[t] = mfma16(af, bf, acc1[t]);
            }
        }
#pragma unroll
        for (int t = 0; t < 4; ++t) {
#pragma unroll
            for (int j = 0; j < 4; ++j) {
                int nd = min(node0 + kg * 4 + j, n - 1);
                acc1[t][j] += bp_c[t] + x[(size_t)nd * 64 + t * 16 + cl];
            }
        }

        // ---- LN2 over 64 channels of rows r = kg*4+j ----
        float mean[4], rstd[4];
#pragma unroll
        for (int j = 0; j < 4; ++j) {
            float s1 = acc1[0][j] + acc1[1][j] + acc1[2][j] + acc1[3][j];
            float s2 = acc1[0][j] * acc1[0][j] + acc1[1][j] * acc1[1][j]
                     + acc1[2][j] * acc1[2][j] + acc1[3][j] * acc1[3][j];
#pragma unroll
            for (int m = 1; m < 16; m <<= 1) {
                s1 += __shfl_xor(s1, m);
                s2 += __shfl_xor(s2, m);
            }
            mean[j] = s1 * 0.015625f;
            float var = s2 * 0.015625f - mean[j] * mean[j];
            rstd[j] = rsqrtf(var + 1e-5f);
        }
#pragma unroll
        for (int t = 0; t < 4; ++t)
#pragma unroll
            for (int j = 0; j < 4; ++j) {
                float v = (acc1[t][j] - mean[j]) * rstd[j] * g2_c[t] + b2_c[t];
                h2[(kg * 4 + j) * H_S + t * 16 + cl] = bf16r(v);
            }
        asm volatile("s_waitcnt lgkmcnt(0)" ::: "memory");

        // ---- GEMM2: f = h2(16x64) @ W1 + b1; gelu -> h3 ----
        f32x4 acc2[4];
#pragma unroll
        for (int t = 0; t < 4; ++t)
            acc2[t] = (f32x4){b1_c[t], b1_c[t], b1_c[t], b1_c[t]};
#pragma unroll
        for (int s = 0; s < 2; ++s) {
            bf16x8 af = frag_ld(h2 + cl * H_S + s * 32 + kg * 8);
#pragma unroll
            for (int t = 0; t < 4; ++t) {
                bf16x8 bf = frag_ld(sW + W1_OFF + (t * 16 + cl) * 88 + s * 32 + kg * 8);
                acc2[t] = mfma16(af, bf, acc2[t]);
            }
        }
#pragma unroll
        for (int t = 0; t < 4; ++t)
#pragma unroll
            for (int j = 0; j < 4; ++j) {
                float v = acc2[t][j];
                v = 0.5f * v * (1.0f + erff(v * 0.70710678118654752f));
                h3[(kg * 4 + j) * H_S + t * 16 + cl] = bf16r(v);
            }
        asm volatile("s_waitcnt lgkmcnt(0)" ::: "memory");

        // ---- GEMM3: y = gelu @ W2 + b2f + acc1 (residual 2) ----
        f32x4 acc3[4];
#pragma unroll
        for (int t = 0; t < 4; ++t) {
            acc3[t] = acc1[t];
#pragma unroll
            for (int j = 0; j < 4; ++j) acc3[t][j] += bf2_c[t];
        }
#pragma unroll
        for (int s = 0; s < 2; ++s) {
            bf16x8 af = frag_ld(h3 + cl * H_S + s * 32 + kg * 8);
#pragma unroll
            for (int t = 0; t < 4; ++t) {
                bf16x8 bf = frag_ld(sW + W2_OFF + (t * 16 + cl) * 88 + s * 32 + kg * 8);
                acc3[t] = mfma16(af, bf, acc3[t]);
            }
        }
#pragma unroll
        for (int t = 0; t < 4; ++t)
#pragma unroll
            for (int j = 0; j < 4; ++j) {
                int r = node0 + kg * 4 + j;
                if (r < n) out[(size_t)r * 64 + t * 16 + cl] = acc3[t][j];
            }
    }
}

extern "C" void kernel_launch(void* const* d_in, const int* in_sizes, int n_in,
                              void* d_out, int out_size, void* d_ws, size_t ws_size,
                              hipStream_t stream) {
    const float* x  = (const float*)d_in[0];
    const int*   ei = (const int*)d_in[1];
    const float* ea = (const float*)d_in[2];
    const float* Wq = (const float*)d_in[3];
    const float* bq = (const float*)d_in[4];
    const float* Wk = (const float*)d_in[5];
    const float* bk = (const float*)d_in[6];
    const float* Wv = (const float*)d_in[7];
    const float* bv = (const float*)d_in[8];
    const float* We = (const float*)d_in[9];
    const float* Wp = (const float*)d_in[10];
    const float* bp = (const float*)d_in[11];
    const float* g1 = (const float*)d_in[12];
    const float* b1 = (const float*)d_in[13];
    const float* g2 = (const float*)d_in[14];
    const float* b2 = (const float*)d_in[15];
    const float* W1 = (const float*)d_in[16];
    const float* b1f = (const float*)d_in[17];
    const float* W2 = (const float*)d_in[18];
    const float* b2f = (const float*)d_in[19];

    const int n = in_sizes[0] / 64;   // 50000
    const int E = in_sizes[2] / 32;   // 600000

    // Workspace carve (~90 MB).
    char* p = (char*)d_ws;
    unsigned* qx = (unsigned*)p; p += (size_t)n * 128 * 4;   // q bf16 + wq fused
    unsigned* kbf = (unsigned*)p; p += (size_t)n * 64 * 4;
    unsigned* vbf = (unsigned*)p; p += (size_t)n * 64 * 4;
    int* deg   = (int*)p;   p += (size_t)n * 4;
    p = (char*)(((uintptr_t)p + 15) & ~(uintptr_t)15);
    int* bucket_e = (int*)p; p += (size_t)n * 64 * 4;
    unsigned short* bucket_s = (unsigned short*)p; p += (size_t)n * 64 * 2;
    p = (char*)(((uintptr_t)p + 15) & ~(uintptr_t)15);
    unsigned* aggs = (unsigned*)p; p += (size_t)n * 96 * 4;   // 192 bf16/node
    unsigned short* wsW = (unsigned short*)p; p += W_TOT * 2;
    unsigned short* wcat = (unsigned short*)p; p += (size_t)WC_TOT * 2;
    float* bcat = (float*)p; p += 448 * 4;

    k_pre<<<196, 256, 0, stream>>>(Wq, Wk, Wv, We, Wp, W1, W2, bq, bk, bv,
                                   wsW, wcat, bcat, deg, n);
    k_bucket<<<(E + 255) / 256, 256, 0, stream>>>(ei, deg, bucket_e, bucket_s,
                                                  E, n);
    k_qkv<<<(n + 63) / 64, 256, 0, stream>>>(x, wcat, bcat, g1, b1,
                                             qx, kbf, vbf, n);
    k_attn<<<(n + 3) / 4, 256, 0, stream>>>(qx, kbf, vbf, ea, deg,
                                            bucket_e, bucket_s, aggs, n, E);
    int nb16 = (n + 15) >> 4;
    int blocks = (nb16 + 3) / 4;
    if (blocks > 391) blocks = 391;   // 2 blocks/CU resident, waves grid-stride
    k_post<<<blocks, 256, 0, stream>>>((const unsigned short*)aggs, wsW,
                                       bp, x, g2, b2, b1f, b2f,
                                       (float*)d_out, n);
}